// Round 13
// baseline (1650.154 us; speedup 1.0000x reference)
//
#include <hip/hip_runtime.h>
#include <hip/hip_bf16.h>
#include <math.h>

// ---------------- problem constants ----------------
#define Dm    512
#define Hh    8
#define NLay  6
#define DFFm  2048
#define Bb    4
#define NTOK  2048          // B * S
#define PADID 1
#define LNEPS 1e-5f
#define S2W   262144        // 512*512 elements

typedef __attribute__((ext_vector_type(8))) short short8;   // 8 x bf16
typedef __attribute__((ext_vector_type(4))) float f32x4;
typedef unsigned short u16;

__device__ __forceinline__ u16 f2bf(float f) {
    union { float f; unsigned int i; } x; x.f = f;
    unsigned int r = x.i + 0x7fffu + ((x.i >> 16) & 1u);   // RNE
    return (u16)(r >> 16);
}

// async global->LDS, 16B per lane (dest linear-in-lane: base+lane*16)
typedef const __attribute__((address_space(1))) void* as1cv;
typedef __attribute__((address_space(3))) void* as3v;
__device__ __forceinline__ void gl_lds16(const u16* g, u16* l) {
    __builtin_amdgcn_global_load_lds((as1cv)g, (as3v)l, 16, 0, 0);
}

// counted-vmcnt sync (T3/T4): wait all but newest N loads, raw barrier, fence
#define SYNC_VM(N) do { \
    asm volatile("s_waitcnt vmcnt(" #N ")" ::: "memory"); \
    __builtin_amdgcn_s_barrier(); \
    __builtin_amdgcn_sched_barrier(0); \
} while (0)

// bijective XCD-chunk swizzle (m204), M fastest within an XCD's chunk.
__device__ __forceinline__ void swz_tile(int& mt, int& nt) {
    const int nwg  = gridDim.x * gridDim.y;
    const int orig = blockIdx.y * gridDim.x + blockIdx.x;
    const int q8 = nwg >> 3, r8 = nwg & 7;
    const int xcd = orig & 7, idx = orig >> 3;
    const int wgid = (xcd < r8 ? xcd * (q8 + 1) : r8 * (q8 + 1) + (xcd - r8) * q8) + idx;
    const int MT = gridDim.y;
    mt = wgid % MT;
    nt = wgid / MT;
}

// ---- one-launch f32->bf16 conversion of all 17 weight tensors ----
struct CvtJobs {
    const float* s[17];
    u16*         d[17];
    long         n4[17];
};
__global__ __launch_bounds__(256) void cvt_many(CvtJobs j) {
    const int job = blockIdx.y;
    const long n4 = j.n4[job];
    const float* in = j.s[job];
    u16* out = j.d[job];
    long i = (long)blockIdx.x * 256 + threadIdx.x;
    const long stride = (long)gridDim.x * 256;
    for (; i < n4; i += stride) {
        float4 v = ((const float4*)in)[i];
        ushort4 o;
        o.x = f2bf(v.x); o.y = f2bf(v.y); o.z = f2bf(v.z); o.w = f2bf(v.w);
        ((ushort4*)out)[i] = o;
    }
}

// ---------------------------------------------------------------------------
// gemm_bt v3: 64x64 tile, BK=32, 3-buffer counted-vmcnt pipeline.
// LDS = 3*(64x32)*2B*2 = 24 KB -> 6 blocks/CU (up from 5) AND loads for tile
// k+2 stay in flight across the barrier (vmcnt(2) waits only tile k+1's pair).
// Chunk swizzle c^((r>>1)&3) (R5-verified conflict-free at BK=32).
// Per-512-col part p = n0>>9 selects (A0..A2, B0..B2); if B1==nullptr, B is
// contiguous and n indexes B0 directly. Split-K: grid.z slices of Kc; ns>1 ->
// unsafeAtomicAdd f32 into Cf (bias from z==0 only).
// ns==1 epilogue: nl >= vth -> vt[b][nl-vth][s]; else C[ml*csm + nl + koff].
// ---------------------------------------------------------------------------
__global__ __launch_bounds__(256) void gemm_bt(
    const u16* __restrict__ A0, const u16* __restrict__ A1,
    const u16* __restrict__ A2, int lda,
    const u16* __restrict__ B0, const u16* __restrict__ B1,
    const u16* __restrict__ B2, int ldb,
    float* Cf, u16* Cb, int csm,
    const float* __restrict__ bias, int relu,
    int Kc, int ns, int vth, int koff, u16* vtp)
{
    __shared__ u16 As[3][2048];   // 64 rows x 32 k
    __shared__ u16 Bs[3][2048];
    int mt, nt; swz_tile(mt, nt);
    const int m0 = mt << 6, n0 = nt << 6;
    const int t = threadIdx.x, lane = t & 63, wave = t >> 6;
    const int wr = (wave >> 1) << 5, wc = (wave & 1) << 5;
    const int fr = lane & 15, fq = lane >> 4;
    const int srow = t >> 2;                      // 0..63
    const int sch  = (t & 3) ^ ((srow >> 1) & 3); // pre-swizzled source chunk

    const int p = n0 >> 9;
    const u16* Amat = (p == 0) ? A0 : (p == 1 ? A1 : A2);
    const u16* Bmat; int nb;
    if (B1) { Bmat = (p == 0) ? B0 : (p == 1 ? B1 : B2); nb = n0 & 511; }
    else    { Bmat = B0; nb = n0; }
    const long kb = (long)blockIdx.z * Kc;

    const u16* Ag = Amat + (long)(m0 + srow) * lda + kb + (sch << 3);
    const u16* Bg = Bmat + (long)(nb + srow) * ldb + kb + (sch << 3);

    f32x4 acc[2][2];
    #pragma unroll
    for (int i = 0; i < 2; i++)
        #pragma unroll
        for (int j = 0; j < 2; j++) acc[i][j] = (f32x4){0.f, 0.f, 0.f, 0.f};

    const int nk = Kc >> 5;
    auto stage = [&](int ki, int buf) {
        const int ko = ki << 5;
        gl_lds16(Ag + ko, &As[buf][t << 3]);
        gl_lds16(Bg + ko, &Bs[buf][t << 3]);
    };
    stage(0, 0);
    if (nk > 1) { stage(1, 1); SYNC_VM(2); }
    else        { SYNC_VM(0); }

    int cur = 0;
    for (int ki = 0; ki < nk; ki++) {
        const bool st = (ki + 2 < nk);
        if (st) stage(ki + 2, cur == 0 ? 2 : cur - 1);
        const int r0 = wr + fr, r1 = wr + 16 + fr;
        const int c0 = wc + fr, c1 = wc + 16 + fr;
        short8 af0 = *(const short8*)&As[cur][(r0 << 5) + ((fq ^ ((r0 >> 1) & 3)) << 3)];
        short8 af1 = *(const short8*)&As[cur][(r1 << 5) + ((fq ^ ((r1 >> 1) & 3)) << 3)];
        short8 bf0 = *(const short8*)&Bs[cur][(c0 << 5) + ((fq ^ ((c0 >> 1) & 3)) << 3)];
        short8 bf1 = *(const short8*)&Bs[cur][(c1 << 5) + ((fq ^ ((c1 >> 1) & 3)) << 3)];
        acc[0][0] = __builtin_amdgcn_mfma_f32_16x16x32_bf16(af0, bf0, acc[0][0], 0, 0, 0);
        acc[0][1] = __builtin_amdgcn_mfma_f32_16x16x32_bf16(af0, bf1, acc[0][1], 0, 0, 0);
        acc[1][0] = __builtin_amdgcn_mfma_f32_16x16x32_bf16(af1, bf0, acc[1][0], 0, 0, 0);
        acc[1][1] = __builtin_amdgcn_mfma_f32_16x16x32_bf16(af1, bf1, acc[1][1], 0, 0, 0);
        if (ki + 1 < nk) {
            if (st) SYNC_VM(2);
            else    SYNC_VM(0);
        }
        cur = (cur == 2) ? 0 : cur + 1;
    }

    #pragma unroll
    for (int i = 0; i < 2; i++) {
        #pragma unroll
        for (int j = 0; j < 2; j++) {
            const int nl  = n0 + wc + (j << 4) + fr;
            const int mlb = m0 + wr + (i << 4) + (fq << 2);
            const float bsv = bias ? bias[nl] : 0.f;
            #pragma unroll
            for (int r = 0; r < 4; r++) {
                const int ml = mlb + r;
                if (ns > 1) {
                    float v = acc[i][j][r] + (blockIdx.z == 0 ? bsv : 0.f);
                    unsafeAtomicAdd(&Cf[(long)ml * csm + nl + koff], v);
                } else {
                    float v = acc[i][j][r] + bsv;
                    if (nl >= vth) {
                        vtp[(long)(ml >> 9) * S2W + (long)(nl - vth) * 512 + (ml & 511)] = f2bf(v);
                    } else {
                        if (relu) v = fmaxf(v, 0.f);
                        long ci = (long)ml * csm + nl + koff;
                        if (Cf) Cf[ci] = v;
                        if (Cb) Cb[ci] = f2bf(v);
                    }
                }
            }
        }
    }
}

// ---------------------------------------------------------------------------
// gemm_kv6: all 6 decoder cross-attn K/V projections in ONE dispatch.
// Same BK=32 3-buffer structure. z = layer; part 0 -> K, part 1 -> V^T.
// ---------------------------------------------------------------------------
__global__ __launch_bounds__(256) void gemm_kv6(
    const u16* __restrict__ A,
    const u16* __restrict__ Wk, const u16* __restrict__ Wv,
    u16* __restrict__ kc, u16* __restrict__ vtc)
{
    __shared__ u16 As[3][2048];
    __shared__ u16 Bs[3][2048];
    int mt, nt; swz_tile(mt, nt);
    const int m0 = mt << 6, n0 = nt << 6;
    const int z = blockIdx.z;
    const int t = threadIdx.x, lane = t & 63, wave = t >> 6;
    const int wr = (wave >> 1) << 5, wc = (wave & 1) << 5;
    const int fr = lane & 15, fq = lane >> 4;
    const int srow = t >> 2;
    const int sch  = (t & 3) ^ ((srow >> 1) & 3);

    const int p = n0 >> 9;
    const u16* Bmat = ((p == 0) ? Wk : Wv) + (size_t)z * S2W;
    const int nb = n0 & 511;

    const u16* Ag = A + (long)(m0 + srow) * 512 + (sch << 3);
    const u16* Bg = Bmat + (long)(nb + srow) * 512 + (sch << 3);

    f32x4 acc[2][2];
    #pragma unroll
    for (int i = 0; i < 2; i++)
        #pragma unroll
        for (int j = 0; j < 2; j++) acc[i][j] = (f32x4){0.f, 0.f, 0.f, 0.f};

    auto stage = [&](int ki, int buf) {
        const int ko = ki << 5;
        gl_lds16(Ag + ko, &As[buf][t << 3]);
        gl_lds16(Bg + ko, &Bs[buf][t << 3]);
    };
    stage(0, 0);
    stage(1, 1);
    SYNC_VM(2);

    int cur = 0;
    for (int ki = 0; ki < 16; ki++) {
        const bool st = (ki + 2 < 16);
        if (st) stage(ki + 2, cur == 0 ? 2 : cur - 1);
        const int r0 = wr + fr, r1 = wr + 16 + fr;
        const int c0 = wc + fr, c1 = wc + 16 + fr;
        short8 af0 = *(const short8*)&As[cur][(r0 << 5) + ((fq ^ ((r0 >> 1) & 3)) << 3)];
        short8 af1 = *(const short8*)&As[cur][(r1 << 5) + ((fq ^ ((r1 >> 1) & 3)) << 3)];
        short8 bf0 = *(const short8*)&Bs[cur][(c0 << 5) + ((fq ^ ((c0 >> 1) & 3)) << 3)];
        short8 bf1 = *(const short8*)&Bs[cur][(c1 << 5) + ((fq ^ ((c1 >> 1) & 3)) << 3)];
        acc[0][0] = __builtin_amdgcn_mfma_f32_16x16x32_bf16(af0, bf0, acc[0][0], 0, 0, 0);
        acc[0][1] = __builtin_amdgcn_mfma_f32_16x16x32_bf16(af0, bf1, acc[0][1], 0, 0, 0);
        acc[1][0] = __builtin_amdgcn_mfma_f32_16x16x32_bf16(af1, bf0, acc[1][0], 0, 0, 0);
        acc[1][1] = __builtin_amdgcn_mfma_f32_16x16x32_bf16(af1, bf1, acc[1][1], 0, 0, 0);
        if (ki + 1 < 16) {
            if (st) SYNC_VM(2);
            else    SYNC_VM(0);
        }
        cur = (cur == 2) ? 0 : cur + 1;
    }

    #pragma unroll
    for (int i = 0; i < 2; i++) {
        #pragma unroll
        for (int j = 0; j < 2; j++) {
            const int nl  = n0 + wc + (j << 4) + fr;
            const int mlb = m0 + wr + (i << 4) + (fq << 2);
            #pragma unroll
            for (int r = 0; r < 4; r++) {
                const int ml = mlb + r;
                const u16 v = f2bf(acc[i][j][r]);
                if (nl < 512)
                    kc[(long)z * NTOK * 512 + (long)ml * 512 + nl] = v;
                else
                    vtc[(long)z * Bb * S2W + (long)(ml >> 9) * S2W +
                        (long)(nl - 512) * 512 + (ml & 511)] = v;
            }
        }
    }
}

// ---------------------------------------------------------------------------
// gemm_big: 128x128 tile, BK=32, 3-buffer counted-vmcnt pipeline.
// Logits GEMM only (f32 out).
// ---------------------------------------------------------------------------
__global__ __launch_bounds__(256) void gemm_big(
    const u16* __restrict__ A, int lda,
    const u16* __restrict__ B, int ldb,
    float* Cf, int ldc,
    const float* __restrict__ bias, int K)
{
    __shared__ u16 As[3][4096];
    __shared__ u16 Bs[3][4096];
    int mt, nt; swz_tile(mt, nt);
    const int m0 = mt << 7, n0 = nt << 7;
    const int t = threadIdx.x, lane = t & 63, wave = t >> 6;
    const int wr = (wave >> 1) << 6, wc = (wave & 1) << 6;
    const int fr = lane & 15, fq = lane >> 4;
    const int srow = t >> 2;
    const int sch  = (t & 3) ^ ((srow >> 1) & 3);
    const u16* Ag0 = A + (long)(m0 + srow) * lda + (sch << 3);
    const u16* Ag1 = A + (long)(m0 + 64 + srow) * lda + (sch << 3);
    const u16* Bg0 = B + (long)(n0 + srow) * ldb + (sch << 3);
    const u16* Bg1 = B + (long)(n0 + 64 + srow) * ldb + (sch << 3);

    f32x4 acc[4][4];
    #pragma unroll
    for (int i = 0; i < 4; i++)
        #pragma unroll
        for (int j = 0; j < 4; j++) acc[i][j] = (f32x4){0.f, 0.f, 0.f, 0.f};

    const int nk = K >> 5;
    auto stage = [&](int ki, int buf) {
        const int ko = ki << 5;
        gl_lds16(Ag0 + ko, &As[buf][t << 3]);
        gl_lds16(Ag1 + ko, &As[buf][(t + 256) << 3]);
        gl_lds16(Bg0 + ko, &Bs[buf][t << 3]);
        gl_lds16(Bg1 + ko, &Bs[buf][(t + 256) << 3]);
    };
    stage(0, 0);
    if (nk > 1) { stage(1, 1); SYNC_VM(4); }
    else        { SYNC_VM(0); }

    int cur = 0;
    for (int ki = 0; ki < nk; ki++) {
        const bool st = (ki + 2 < nk);
        if (st) stage(ki + 2, cur == 0 ? 2 : cur - 1);
        short8 af[4], bf[4];
        #pragma unroll
        for (int i = 0; i < 4; i++) {
            const int r = wr + (i << 4) + fr;
            af[i] = *(const short8*)&As[cur][(r << 5) + ((fq ^ ((r >> 1) & 3)) << 3)];
        }
        #pragma unroll
        for (int j = 0; j < 4; j++) {
            const int c = wc + (j << 4) + fr;
            bf[j] = *(const short8*)&Bs[cur][(c << 5) + ((fq ^ ((c >> 1) & 3)) << 3)];
        }
        #pragma unroll
        for (int i = 0; i < 4; i++)
            #pragma unroll
            for (int j = 0; j < 4; j++)
                acc[i][j] = __builtin_amdgcn_mfma_f32_16x16x32_bf16(af[i], bf[j], acc[i][j], 0, 0, 0);
        if (ki + 1 < nk) {
            if (st) SYNC_VM(4);
            else    SYNC_VM(0);
        }
        cur = (cur == 2) ? 0 : cur + 1;
    }

    #pragma unroll
    for (int i = 0; i < 4; i++) {
        #pragma unroll
        for (int j = 0; j < 4; j++) {
            const int nl  = n0 + wc + (j << 4) + fr;
            const int mlb = m0 + wr + (i << 4) + (fq << 2);
            const float bsv = bias ? bias[nl] : 0.f;
            #pragma unroll
            for (int r = 0; r < 4; r++)
                Cf[(long)(mlb + r) * ldc + nl] = acc[i][j][r] + bsv;
        }
    }
}

// ---------------------------------------------------------------------------
// Fused attention v2 (KV-split-2): block per (q-tile 32, head, batch),
// 4 waves = {2 q-halves x 2 kv-halves}; flash combine via LDS at the end.
// ---------------------------------------------------------------------------
__global__ __launch_bounds__(256) void attn_fused(
    const u16* __restrict__ qkb, const u16* __restrict__ kb_, int ldk,
    const u16* __restrict__ vt,
    const int* __restrict__ ids, u16* __restrict__ attc, int causal)
{
    __shared__ u16 Ks[2][4096];      // [kv-half][64 keys x 64 d]
    __shared__ u16 Vs[2][4096];      // [kv-half][64 d x 64 s]
    __shared__ short Ps[4][16][72];
    const int t = threadIdx.x, lane = t & 63, w = t >> 6;
    const int fr = lane & 15, fq = lane >> 4;
    const int qh = w & 1, kvh = w >> 1;
    const int q0 = blockIdx.x << 5, h = blockIdx.y, b = blockIdx.z;

    const u16* qp = qkb + (long)(b * 512 + q0 + (qh << 4) + fr) * 1024 + h * 64 + (fq << 3);
    short8 aq0 = *(const short8*)qp;
    short8 aq1 = *(const short8*)(qp + 32);

    const int sr = t >> 3, sc = (t & 7) ^ (sr & 7);
    const u16* kg0 = kb_ + (long)(b * 512 + sr) * ldk + h * 64 + (sc << 3);
    const u16* kg1 = kg0 + 32L * ldk;
    const u16* vg0 = vt + (long)b * S2W + (long)(h * 64 + sr) * 512 + (sc << 3);
    const u16* vg1 = vg0 + 32L * 512;

    unsigned pmask = 0;
    #pragma unroll
    for (int kt = 0; kt < 8; kt++)
        #pragma unroll
        for (int j = 0; j < 4; j++)
            if (ids[b * 512 + (kt << 6) + (j << 4) + fr] == PADID)
                pmask |= 1u << ((kt << 2) + j);

    const int nkt = causal ? (((q0 + 31) >> 6) + 1) : 8;
    const int nA = (nkt + 1) >> 1, nB = nkt - nA;
    const int myn = kvh ? nB : nA;

    float m[4], l[4]; f32x4 oc[4];
    #pragma unroll
    for (int r = 0; r < 4; r++) { m[r] = -INFINITY; l[r] = 0.f; oc[r] = (f32x4){0.f,0.f,0.f,0.f}; }

    for (int i = 0; i < nA; i++) {
        {
            const long soA = (long)(i << 6);
            gl_lds16(kg0 + soA * ldk, &Ks[0][t << 3]);
            gl_lds16(kg1 + soA * ldk, &Ks[0][(t + 256) << 3]);
            gl_lds16(vg0 + soA,       &Vs[0][t << 3]);
            gl_lds16(vg1 + soA,       &Vs[0][(t + 256) << 3]);
            if (i < nB) {
                const long soB = (long)((nA + i) << 6);
                gl_lds16(kg0 + soB * ldk, &Ks[1][t << 3]);
                gl_lds16(kg1 + soB * ldk, &Ks[1][(t + 256) << 3]);
                gl_lds16(vg0 + soB,       &Vs[1][t << 3]);
                gl_lds16(vg1 + soB,       &Vs[1][(t + 256) << 3]);
            }
        }
        __syncthreads();

        if (i < myn) {
            const int kt = (kvh ? nA : 0) + i;
            f32x4 sc4[4];
            #pragma unroll
            for (int j = 0; j < 4; j++) sc4[j] = (f32x4){0.f,0.f,0.f,0.f};
            #pragma unroll
            for (int j = 0; j < 4; j++) {
                const int rr = (j << 4) + fr;
                short8 bk0 = *(const short8*)&Ks[kvh][rr * 64 + ((fq ^ (rr & 7)) << 3)];
                short8 bk1 = *(const short8*)&Ks[kvh][rr * 64 + (((fq | 4) ^ (rr & 7)) << 3)];
                sc4[j] = __builtin_amdgcn_mfma_f32_16x16x32_bf16(aq0, bk0, sc4[j], 0, 0, 0);
                sc4[j] = __builtin_amdgcn_mfma_f32_16x16x32_bf16(aq1, bk1, sc4[j], 0, 0, 0);
            }
            const int s0 = kt << 6;
            #pragma unroll
            for (int r = 0; r < 4; r++) {
                const int qa = q0 + (qh << 4) + (fq << 2) + r;
                float mx = -INFINITY;
                #pragma unroll
                for (int j = 0; j < 4; j++) {
                    bool msk = ((pmask >> ((kt << 2) + j)) & 1) ||
                               (causal && (s0 + (j << 4) + fr) > qa);
                    float sv = msk ? -INFINITY : sc4[j][r] * 0.125f;
                    sc4[j][r] = sv;
                    mx = fmaxf(mx, sv);
                }
                mx = fmaxf(mx, __shfl_xor(mx, 1)); mx = fmaxf(mx, __shfl_xor(mx, 2));
                mx = fmaxf(mx, __shfl_xor(mx, 4)); mx = fmaxf(mx, __shfl_xor(mx, 8));
                float mnew  = fmaxf(m[r], mx);
                float scale = (mnew == -INFINITY) ? 1.f : __expf(m[r] - mnew);
                float ps = 0.f;
                #pragma unroll
                for (int j = 0; j < 4; j++) {
                    float p2 = (sc4[j][r] == -INFINITY) ? 0.f : __expf(sc4[j][r] - mnew);
                    sc4[j][r] = p2; ps += p2;
                }
                ps += __shfl_xor(ps, 1); ps += __shfl_xor(ps, 2);
                ps += __shfl_xor(ps, 4); ps += __shfl_xor(ps, 8);
                l[r] = l[r] * scale + ps;
                m[r] = mnew;
                #pragma unroll
                for (int j2 = 0; j2 < 4; j2++) oc[j2][r] *= scale;
            }
            #pragma unroll
            for (int r = 0; r < 4; r++)
                #pragma unroll
                for (int j = 0; j < 4; j++)
                    Ps[w][(fq << 2) + r][(j << 4) + fr] = (short)f2bf(sc4[j][r]);
            #pragma unroll
            for (int kc2 = 0; kc2 < 2; kc2++) {
                short8 pa = *(const short8*)&Ps[w][fr][(kc2 << 5) + (fq << 3)];
                #pragma unroll
                for (int j2 = 0; j2 < 4; j2++) {
                    const int rd = (j2 << 4) + fr;
                    const int cch = (((kc2 << 2) | fq) ^ (rd & 7));
                    short8 bv = *(const short8*)&Vs[kvh][rd * 64 + (cch << 3)];
                    oc[j2] = __builtin_amdgcn_mfma_f32_16x16x32_bf16(pa, bv, oc[j2], 0, 0, 0);
                }
            }
        }
        __syncthreads();
    }

    // ---- combine kv halves (reuse Ks/Vs LDS) ----
    float* Ob = (float*)&Ks[0][0];
    float* Ml = (float*)&Vs[0][0];
    if (kvh == 1) {
        #pragma unroll
        for (int r = 0; r < 4; r++) {
            const int row = (qh << 4) + (fq << 2) + r;
            Ml[(row << 1)]     = m[r];
            Ml[(row << 1) + 1] = l[r];
            #pragma unroll
            for (int j2 = 0; j2 < 4; j2++)
                Ob[(row << 6) + (j2 << 4) + fr] = oc[j2][r];
        }
    }
    __syncthreads();
    if (kvh == 0) {
        #pragma unroll
        for (int r = 0; r < 4; r++) {
            const int row = (qh << 4) + (fq << 2) + r;
            const float mB = Ml[(row << 1)], lB = Ml[(row << 1) + 1];
            const float mN = fmaxf(m[r], mB);
            float sA, sB;
            if (mN == -INFINITY) { sA = 0.f; sB = 0.f; }
            else {
                sA = (m[r] == -INFINITY) ? 0.f : __expf(m[r] - mN);
                sB = (mB   == -INFINITY) ? 0.f : __expf(mB   - mN);
            }
            const float L = l[r] * sA + lB * sB;
            const float inv = (L > 0.f) ? 1.f / L : 0.f;
            #pragma unroll
            for (int j2 = 0; j2 < 4; j2++) {
                float val = (oc[j2][r] * sA + Ob[(row << 6) + (j2 << 4) + fr] * sB) * inv;
                attc[(long)(b * 512 + q0 + (qh << 4) + (fq << 2) + r) * 512 +
                     h * 64 + (j2 << 4) + fr] = f2bf(val);
            }
        }
    }
}

// LayerNorm over D=512: 4 rows/block (wave per row). f32 in -> bf16 out.
__global__ __launch_bounds__(256) void ln_rows(
    const float* __restrict__ x, const float* __restrict__ g,
    const float* __restrict__ b, u16* __restrict__ out)
{
    int row  = blockIdx.x * 4 + (threadIdx.x >> 6);
    int lane = threadIdx.x & 63;
    const float* xr = x + (long)row * Dm;
    float v[8]; float s = 0.f;
    #pragma unroll
    for (int i = 0; i < 8; i++) { v[i] = xr[lane + (i << 6)]; s += v[i]; }
    #pragma unroll
    for (int o = 32; o > 0; o >>= 1) s += __shfl_xor(s, o);
    float mean = s * (1.f / 512.f);
    float q = 0.f;
    #pragma unroll
    for (int i = 0; i < 8; i++) { float d = v[i] - mean; q += d * d; }
    #pragma unroll
    for (int o = 32; o > 0; o >>= 1) q += __shfl_xor(q, o);
    float rinv = rsqrtf(q * (1.f / 512.f) + LNEPS);
    u16* orow = out + (long)row * Dm;
    #pragma unroll
    for (int i = 0; i < 8; i++) {
        int c = lane + (i << 6);
        orow[c] = f2bf((v[i] - mean) * rinv * g[c] + b[c]);
    }
}

// x[b,s,:] = embed[id]*sqrt(D) + PE(s,:)   (f32 in/out)
__global__ __launch_bounds__(256) void embed_pe(
    const int* __restrict__ ids, const float* __restrict__ emb,
    float* __restrict__ out)
{
    int idx = blockIdx.x * 256 + threadIdx.x;   // NTOK*512 = 2^20
    int d   = idx & 511;
    int tok = idx >> 9;
    int s   = tok & 511;
    int id  = ids[tok];
    float val = emb[(long)id * Dm + d] * 22.62741699796952f;     // sqrt(512)
    int i2 = d >> 1;
    float dv  = expf((float)(i2 << 1) * (-9.210340371976184f / 512.f));
    float ang = (float)s * dv;
    val += (d & 1) ? cosf(ang) : sinf(ang);
    out[idx] = val;
}

// ---------------------------------------------------------------------------
extern "C" void kernel_launch(void* const* d_in, const int* in_sizes, int n_in,
                              void* d_out, int out_size, void* d_ws, size_t ws_size,
                              hipStream_t stream)
{
    (void)in_sizes; (void)n_in; (void)out_size; (void)ws_size;
    const int*   src       = (const int*)d_in[0];
    const int*   tgt       = (const int*)d_in[1];
    const float* src_embed = (const float*)d_in[2];
    const float* tgt_embed = (const float*)d_in[3];
    const float* enc_b1  = (const float*)d_in[9];
    const float* enc_b2  = (const float*)d_in[11];
    const float* enc_ln1g = (const float*)d_in[12];
    const float* enc_ln1b = (const float*)d_in[13];
    const float* enc_ln2g = (const float*)d_in[14];
    const float* enc_ln2b = (const float*)d_in[15];
    const float* enc_lnfg = (const float*)d_in[16];
    const float* enc_lnfb = (const float*)d_in[17];
    const float* dec_b1  = (const float*)d_in[27];
    const float* dec_b2  = (const float*)d_in[29];
    const float* dec_ln1g = (const float*)d_in[30];
    const float* dec_ln1b = (const float*)d_in[31];
    const float* dec_ln2g = (const float*)d_in[32];
    const float* dec_ln2b = (const float*)d_in[33];
    const float* dec_ln3g = (const float*)d_in[34];
    const float* dec_ln3b = (const float*)d_in[35];
    const float* dec_lnfg = (const float*)d_in[36];
    const float* dec_lnfb = (const float*)d_in[37];
    const float* out_b  = (const float*)d_in[39];

    char* wp = (char*)d_ws;
    auto carve = [&](size_t nbytes) {
        void* p = (void*)wp; wp += (nbytes + 255) & ~(size_t)255; return p;
    };

    const long nW = (long)NLay * S2W;
    const long nF = (long)NLay * DFFm * Dm;
    const long nO = 32000L * Dm;

    u16* Wb[12];
    for (int i = 0; i < 12; i++) Wb[i] = (u16*)carve((size_t)nW * 2);
    u16* w1E  = (u16*)carve((size_t)nF * 2);
    u16* w2E  = (u16*)carve((size_t)nF * 2);
    u16* w1D  = (u16*)carve((size_t)nF * 2);
    u16* w2D  = (u16*)carve((size_t)nF * 2);
    u16* outW = (u16*)carve((size_t)nO * 2);

    float* x  = (float*)carve((size_t)NTOK * Dm * 4);
    float* y  = (float*)carve((size_t)NTOK * Dm * 4);
    u16* nrm  = (u16*)carve((size_t)NTOK * Dm * 2);
    u16* qkb  = (u16*)carve((size_t)NTOK * 1024 * 2);
    u16* vt   = (u16*)carve((size_t)Bb * Dm * 512 * 2);
    u16* attc = (u16*)carve((size_t)NTOK * Dm * 2);
    u16* h1   = (u16*)carve((size_t)NTOK * DFFm * 2);
    u16* memn = (u16*)carve((size_t)NTOK * Dm * 2);
    u16* kc6  = (u16*)carve((size_t)NLay * NTOK * 512 * 2);   // cross K, per layer
    u16* vt6  = (u16*)carve((size_t)NLay * Bb * S2W * 2);     // cross V^T, per layer

    const int wi[12] = {4, 5, 6, 7, 18, 19, 20, 21, 22, 23, 24, 25};
    CvtJobs jobs;
    for (int i = 0; i < 12; i++) {
        jobs.s[i] = (const float*)d_in[wi[i]]; jobs.d[i] = Wb[i]; jobs.n4[i] = nW >> 2;
    }
    jobs.s[12] = (const float*)d_in[8];  jobs.d[12] = w1E;  jobs.n4[12] = nF >> 2;
    jobs.s[13] = (const float*)d_in[10]; jobs.d[13] = w2E;  jobs.n4[13] = nF >> 2;
    jobs.s[14] = (const float*)d_in[26]; jobs.d[14] = w1D;  jobs.n4[14] = nF >> 2;
    jobs.s[15] = (const float*)d_in[28]; jobs.d[15] = w2D;  jobs.n4[15] = nF >> 2;
    jobs.s[16] = (const float*)d_in[38]; jobs.d[16] = outW; jobs.n4[16] = nO >> 2;
    cvt_many<<<dim3(512, 17), 256, 0, stream>>>(jobs);

    const int BIG = 1 << 28;
    u16 *eWq = Wb[0], *eWk = Wb[1], *eWv = Wb[2], *eWo = Wb[3];
    u16 *sWq = Wb[4], *sWk = Wb[5], *sWv = Wb[6], *sWo = Wb[7];
    u16 *cWq = Wb[8], *cWk = Wb[9], *cWv = Wb[10], *cWo = Wb[11];

    // ---------------- Encoder ----------------
    embed_pe<<<4096, 256, 0, stream>>>(src, src_embed, x);
    for (int l = 0; l < NLay; l++) {
        const size_t wo = (size_t)l * S2W;
        ln_rows<<<512, 256, 0, stream>>>(x, enc_ln1g + l * Dm, enc_ln1b + l * Dm, nrm);
        gemm_bt<<<dim3(24, 32, 1), 256, 0, stream>>>(nrm, nrm, nrm, 512,
            eWq + wo, eWk + wo, eWv + wo, 512,
            nullptr, qkb, 1024, nullptr, 0, 512, 1, 1024, 0, vt);
        attn_fused<<<dim3(16, Hh, Bb), 256, 0, stream>>>(qkb, qkb + 512, 1024, vt, src, attc, 0);
        gemm_bt<<<dim3(8, 32, 2), 256, 0, stream>>>(attc, attc, attc, 512,
            eWo + wo, nullptr, nullptr, 512,
            x, nullptr, 512, nullptr, 0, 256, 2, BIG, 0, nullptr);
        ln_rows<<<512, 256, 0, stream>>>(x, enc_ln2g + l * Dm, enc_ln2b + l * Dm, nrm);
        gemm_bt<<<dim3(32, 32, 1), 256, 0, stream>>>(nrm, nrm, nrm, 512,
            w1E + (size_t)l * DFFm * Dm, nullptr, nullptr, 512,
            nullptr, h1, DFFm, enc_b1 + l * DFFm, 1, 512, 1, BIG, 0, nullptr);
        gemm_bt<<<dim3(8, 32, 4), 256, 0, stream>>>(h1, h1, h1, DFFm,
            w2E + (size_t)l * Dm * DFFm, nullptr, nullptr, DFFm,
            x, nullptr, 512, enc_b2 + l * Dm, 0, 512, 4, BIG, 0, nullptr);
    }
    ln_rows<<<512, 256, 0, stream>>>(x, enc_lnfg, enc_lnfb, memn);
    gemm_kv6<<<dim3(16, 32, NLay), 256, 0, stream>>>(memn, cWk, cWv, kc6, vt6);

    // ---------------- Decoder ----------------
    embed_pe<<<4096, 256, 0, stream>>>(tgt, tgt_embed, y);
    for (int l = 0; l < NLay; l++) {
        const size_t wo = (size_t)l * S2W;
        // self-attention (causal + tgt pad)
        ln_rows<<<512, 256, 0, stream>>>(y, dec_ln1g + l * Dm, dec_ln1b + l * Dm, nrm);
        gemm_bt<<<dim3(24, 32, 1), 256, 0, stream>>>(nrm, nrm, nrm, 512,
            sWq + wo, sWk + wo, sWv + wo, 512,
            nullptr, qkb, 1024, nullptr, 0, 512, 1, 1024, 0, vt);
        attn_fused<<<dim3(16, Hh, Bb), 256, 0, stream>>>(qkb, qkb + 512, 1024, vt, tgt, attc, 1);
        gemm_bt<<<dim3(8, 32, 2), 256, 0, stream>>>(attc, attc, attc, 512,
            sWo + wo, nullptr, nullptr, 512,
            y, nullptr, 512, nullptr, 0, 256, 2, BIG, 0, nullptr);
        // cross-attention: Q only (K/V precomputed by gemm_kv6)
        ln_rows<<<512, 256, 0, stream>>>(y, dec_ln2g + l * Dm, dec_ln2b + l * Dm, nrm);
        gemm_bt<<<dim3(8, 32, 1), 256, 0, stream>>>(nrm, nrm, nrm, 512,
            cWq + wo, nullptr, nullptr, 512,
            nullptr, qkb, 1024, nullptr, 0, 512, 1, BIG, 0, nullptr);
        attn_fused<<<dim3(16, Hh, Bb), 256, 0, stream>>>(qkb,
            kc6 + (size_t)l * NTOK * 512, 512, vt6 + (size_t)l * Bb * S2W, src, attc, 0);
        gemm_bt<<<dim3(8, 32, 2), 256, 0, stream>>>(attc, attc, attc, 512,
            cWo + wo, nullptr, nullptr, 512,
            y, nullptr, 512, nullptr, 0, 256, 2, BIG, 0, nullptr);
        // FFN
        ln_rows<<<512, 256, 0, stream>>>(y, dec_ln3g + l * Dm, dec_ln3b + l * Dm, nrm);
        gemm_bt<<<dim3(32, 32, 1), 256, 0, stream>>>(nrm, nrm, nrm, 512,
            w1D + (size_t)l * DFFm * Dm, nullptr, nullptr, 512,
            nullptr, h1, DFFm, dec_b1 + l * DFFm, 1, 512, 1, BIG, 0, nullptr);
        gemm_bt<<<dim3(8, 32, 4), 256, 0, stream>>>(h1, h1, h1, DFFm,
            w2D + (size_t)l * Dm * DFFm, nullptr, nullptr, DFFm,
            y, nullptr, 512, dec_b2 + l * Dm, 0, 512, 4, BIG, 0, nullptr);
    }
    ln_rows<<<512, 256, 0, stream>>>(y, dec_lnfg, dec_lnfb, nrm);

    // final projection to vocab: [2048][32000] f32 out
    gemm_big<<<dim3(250, 16), 256, 0, stream>>>(nrm, 512, outW, 512,
        (float*)d_out, 32000, out_b, 512);
}

// Round 14
// 1631.181 us; speedup vs baseline: 1.0116x; 1.0116x over previous
//
#include <hip/hip_runtime.h>
#include <hip/hip_bf16.h>
#include <math.h>

// ---------------- problem constants ----------------
#define Dm    512
#define Hh    8
#define NLay  6
#define DFFm  2048
#define Bb    4
#define NTOK  2048          // B * S
#define PADID 1
#define LNEPS 1e-5f
#define S2W   262144        // 512*512 elements

typedef __attribute__((ext_vector_type(8))) short short8;   // 8 x bf16
typedef __attribute__((ext_vector_type(4))) float f32x4;
typedef unsigned short u16;

__device__ __forceinline__ u16 f2bf(float f) {
    union { float f; unsigned int i; } x; x.f = f;
    unsigned int r = x.i + 0x7fffu + ((x.i >> 16) & 1u);   // RNE
    return (u16)(r >> 16);
}

// async global->LDS, 16B per lane (dest linear-in-lane: base+lane*16)
typedef const __attribute__((address_space(1))) void* as1cv;
typedef __attribute__((address_space(3))) void* as3v;
__device__ __forceinline__ void gl_lds16(const u16* g, u16* l) {
    __builtin_amdgcn_global_load_lds((as1cv)g, (as3v)l, 16, 0, 0);
}

// counted-vmcnt sync (T3/T4) — used in gemm_big only
#define SYNC_VM(N) do { \
    asm volatile("s_waitcnt vmcnt(" #N ")" ::: "memory"); \
    __builtin_amdgcn_s_barrier(); \
    __builtin_amdgcn_sched_barrier(0); \
} while (0)

// bijective XCD-chunk swizzle (m204), M fastest within an XCD's chunk.
__device__ __forceinline__ void swz_tile(int& mt, int& nt) {
    const int nwg  = gridDim.x * gridDim.y;
    const int orig = blockIdx.y * gridDim.x + blockIdx.x;
    const int q8 = nwg >> 3, r8 = nwg & 7;
    const int xcd = orig & 7, idx = orig >> 3;
    const int wgid = (xcd < r8 ? xcd * (q8 + 1) : r8 * (q8 + 1) + (xcd - r8) * q8) + idx;
    const int MT = gridDim.y;
    mt = wgid % MT;
    nt = wgid / MT;
}

// ---- one-launch f32->bf16 conversion of all 17 weight tensors ----
struct CvtJobs {
    const float* s[17];
    u16*         d[17];
    long         n4[17];
};
__global__ __launch_bounds__(256) void cvt_many(CvtJobs j) {
    const int job = blockIdx.y;
    const long n4 = j.n4[job];
    const float* in = j.s[job];
    u16* out = j.d[job];
    long i = (long)blockIdx.x * 256 + threadIdx.x;
    const long stride = (long)gridDim.x * 256;
    for (; i < n4; i += stride) {
        float4 v = ((const float4*)in)[i];
        ushort4 o;
        o.x = f2bf(v.x); o.y = f2bf(v.y); o.z = f2bf(v.z); o.w = f2bf(v.w);
        ((ushort4*)out)[i] = o;
    }
}

// ---------------------------------------------------------------------------
// gemm_bt (R12-proven): 64x64 tile, BK=64, dbuf, one barrier (vmcnt-drain)
// per K-step. Per-512-col part p = n0>>9 selects (A0..A2, B0..B2); if
// B1==nullptr, B is contiguous and n indexes B0. Split-K: grid.z slices of
// Kc; ns>1 -> unsafeAtomicAdd f32 into Cf (bias from z==0 only).
// ns==1 epilogue: nl >= vth -> vt[b][nl-vth][s]; else C[ml*csm + nl + koff].
// ---------------------------------------------------------------------------
__global__ __launch_bounds__(256) void gemm_bt(
    const u16* __restrict__ A0, const u16* __restrict__ A1,
    const u16* __restrict__ A2, int lda,
    const u16* __restrict__ B0, const u16* __restrict__ B1,
    const u16* __restrict__ B2, int ldb,
    float* Cf, u16* Cb, int csm,
    const float* __restrict__ bias, int relu,
    int Kc, int ns, int vth, int koff, u16* vtp)
{
    __shared__ u16 As[2][4096];   // 64 rows x 64 k
    __shared__ u16 Bs[2][4096];
    int mt, nt; swz_tile(mt, nt);
    const int m0 = mt << 6, n0 = nt << 6;
    const int t = threadIdx.x, lane = t & 63, wave = t >> 6;
    const int wr = (wave >> 1) << 5, wc = (wave & 1) << 5;
    const int fr = lane & 15, fq = lane >> 4;
    const int srow = t >> 3;
    const int sch  = (t & 7) ^ (srow & 7);

    const int p = n0 >> 9;
    const u16* Amat = (p == 0) ? A0 : (p == 1 ? A1 : A2);
    const u16* Bmat; int nb;
    if (B1) { Bmat = (p == 0) ? B0 : (p == 1 ? B1 : B2); nb = n0 & 511; }
    else    { Bmat = B0; nb = n0; }
    const long kb = (long)blockIdx.z * Kc;

    const u16* Ag0 = Amat + (long)(m0 + srow) * lda + kb + (sch << 3);
    const u16* Ag1 = Ag0 + 32L * lda;
    const u16* Bg0 = Bmat + (long)(nb + srow) * ldb + kb + (sch << 3);
    const u16* Bg1 = Bg0 + 32L * ldb;

    f32x4 acc[2][2];
    #pragma unroll
    for (int i = 0; i < 2; i++)
        #pragma unroll
        for (int j = 0; j < 2; j++) acc[i][j] = (f32x4){0.f, 0.f, 0.f, 0.f};

    const int nk = Kc >> 6;
    gl_lds16(Ag0, &As[0][t << 3]);
    gl_lds16(Ag1, &As[0][(t + 256) << 3]);
    gl_lds16(Bg0, &Bs[0][t << 3]);
    gl_lds16(Bg1, &Bs[0][(t + 256) << 3]);
    __syncthreads();
    for (int ki = 0; ki < nk; ki++) {
        const int cur = ki & 1;
        if (ki + 1 < nk) {
            const int ko = (ki + 1) << 6;
            gl_lds16(Ag0 + ko, &As[cur ^ 1][t << 3]);
            gl_lds16(Ag1 + ko, &As[cur ^ 1][(t + 256) << 3]);
            gl_lds16(Bg0 + ko, &Bs[cur ^ 1][t << 3]);
            gl_lds16(Bg1 + ko, &Bs[cur ^ 1][(t + 256) << 3]);
        }
        const int r0 = wr + fr, r1 = wr + 16 + fr;
        const int c0 = wc + fr, c1 = wc + 16 + fr;
        #pragma unroll
        for (int h = 0; h < 2; h++) {
            const int lc = fq | (h << 2);
            short8 af0 = *(const short8*)&As[cur][(r0 << 6) + ((lc ^ (r0 & 7)) << 3)];
            short8 af1 = *(const short8*)&As[cur][(r1 << 6) + ((lc ^ (r1 & 7)) << 3)];
            short8 bf0 = *(const short8*)&Bs[cur][(c0 << 6) + ((lc ^ (c0 & 7)) << 3)];
            short8 bf1 = *(const short8*)&Bs[cur][(c1 << 6) + ((lc ^ (c1 & 7)) << 3)];
            acc[0][0] = __builtin_amdgcn_mfma_f32_16x16x32_bf16(af0, bf0, acc[0][0], 0, 0, 0);
            acc[0][1] = __builtin_amdgcn_mfma_f32_16x16x32_bf16(af0, bf1, acc[0][1], 0, 0, 0);
            acc[1][0] = __builtin_amdgcn_mfma_f32_16x16x32_bf16(af1, bf0, acc[1][0], 0, 0, 0);
            acc[1][1] = __builtin_amdgcn_mfma_f32_16x16x32_bf16(af1, bf1, acc[1][1], 0, 0, 0);
        }
        __syncthreads();
    }

    #pragma unroll
    for (int i = 0; i < 2; i++) {
        #pragma unroll
        for (int j = 0; j < 2; j++) {
            const int nl  = n0 + wc + (j << 4) + fr;
            const int mlb = m0 + wr + (i << 4) + (fq << 2);
            const float bsv = bias ? bias[nl] : 0.f;
            #pragma unroll
            for (int r = 0; r < 4; r++) {
                const int ml = mlb + r;
                if (ns > 1) {
                    float v = acc[i][j][r] + (blockIdx.z == 0 ? bsv : 0.f);
                    unsafeAtomicAdd(&Cf[(long)ml * csm + nl + koff], v);
                } else {
                    float v = acc[i][j][r] + bsv;
                    if (nl >= vth) {
                        vtp[(long)(ml >> 9) * S2W + (long)(nl - vth) * 512 + (ml & 511)] = f2bf(v);
                    } else {
                        if (relu) v = fmaxf(v, 0.f);
                        long ci = (long)ml * csm + nl + koff;
                        if (Cf) Cf[ci] = v;
                        if (Cb) Cb[ci] = f2bf(v);
                    }
                }
            }
        }
    }
}

// ---------------------------------------------------------------------------
// gemm_kv6 (R12-proven): all 6 decoder cross K/V projections in one dispatch.
// A = memn [2048][512]; z = layer; part 0 -> K to kc[z], part 1 -> V^T.
// ---------------------------------------------------------------------------
__global__ __launch_bounds__(256) void gemm_kv6(
    const u16* __restrict__ A,
    const u16* __restrict__ Wk, const u16* __restrict__ Wv,
    u16* __restrict__ kc, u16* __restrict__ vtc)
{
    __shared__ u16 As[2][4096];
    __shared__ u16 Bs[2][4096];
    int mt, nt; swz_tile(mt, nt);
    const int m0 = mt << 6, n0 = nt << 6;
    const int z = blockIdx.z;
    const int t = threadIdx.x, lane = t & 63, wave = t >> 6;
    const int wr = (wave >> 1) << 5, wc = (wave & 1) << 5;
    const int fr = lane & 15, fq = lane >> 4;
    const int srow = t >> 3;
    const int sch  = (t & 7) ^ (srow & 7);

    const int p = n0 >> 9;
    const u16* Bmat = ((p == 0) ? Wk : Wv) + (size_t)z * S2W;
    const int nb = n0 & 511;

    const u16* Ag0 = A + (long)(m0 + srow) * 512 + (sch << 3);
    const u16* Ag1 = Ag0 + 32L * 512;
    const u16* Bg0 = Bmat + (long)(nb + srow) * 512 + (sch << 3);
    const u16* Bg1 = Bg0 + 32L * 512;

    f32x4 acc[2][2];
    #pragma unroll
    for (int i = 0; i < 2; i++)
        #pragma unroll
        for (int j = 0; j < 2; j++) acc[i][j] = (f32x4){0.f, 0.f, 0.f, 0.f};

    gl_lds16(Ag0, &As[0][t << 3]);
    gl_lds16(Ag1, &As[0][(t + 256) << 3]);
    gl_lds16(Bg0, &Bs[0][t << 3]);
    gl_lds16(Bg1, &Bs[0][(t + 256) << 3]);
    __syncthreads();
    for (int ki = 0; ki < 8; ki++) {
        const int cur = ki & 1;
        if (ki + 1 < 8) {
            const int ko = (ki + 1) << 6;
            gl_lds16(Ag0 + ko, &As[cur ^ 1][t << 3]);
            gl_lds16(Ag1 + ko, &As[cur ^ 1][(t + 256) << 3]);
            gl_lds16(Bg0 + ko, &Bs[cur ^ 1][t << 3]);
            gl_lds16(Bg1 + ko, &Bs[cur ^ 1][(t + 256) << 3]);
        }
        const int r0 = wr + fr, r1 = wr + 16 + fr;
        const int c0 = wc + fr, c1 = wc + 16 + fr;
        #pragma unroll
        for (int h = 0; h < 2; h++) {
            const int lc = fq | (h << 2);
            short8 af0 = *(const short8*)&As[cur][(r0 << 6) + ((lc ^ (r0 & 7)) << 3)];
            short8 af1 = *(const short8*)&As[cur][(r1 << 6) + ((lc ^ (r1 & 7)) << 3)];
            short8 bf0 = *(const short8*)&Bs[cur][(c0 << 6) + ((lc ^ (c0 & 7)) << 3)];
            short8 bf1 = *(const short8*)&Bs[cur][(c1 << 6) + ((lc ^ (c1 & 7)) << 3)];
            acc[0][0] = __builtin_amdgcn_mfma_f32_16x16x32_bf16(af0, bf0, acc[0][0], 0, 0, 0);
            acc[0][1] = __builtin_amdgcn_mfma_f32_16x16x32_bf16(af0, bf1, acc[0][1], 0, 0, 0);
            acc[1][0] = __builtin_amdgcn_mfma_f32_16x16x32_bf16(af1, bf0, acc[1][0], 0, 0, 0);
            acc[1][1] = __builtin_amdgcn_mfma_f32_16x16x32_bf16(af1, bf1, acc[1][1], 0, 0, 0);
        }
        __syncthreads();
    }

    #pragma unroll
    for (int i = 0; i < 2; i++) {
        #pragma unroll
        for (int j = 0; j < 2; j++) {
            const int nl  = n0 + wc + (j << 4) + fr;
            const int mlb = m0 + wr + (i << 4) + (fq << 2);
            #pragma unroll
            for (int r = 0; r < 4; r++) {
                const int ml = mlb + r;
                const u16 v = f2bf(acc[i][j][r]);
                if (nl < 512)
                    kc[(long)z * NTOK * 512 + (long)ml * 512 + nl] = v;
                else
                    vtc[(long)z * Bb * S2W + (long)(ml >> 9) * S2W +
                        (long)(nl - 512) * 512 + (ml & 511)] = v;
            }
        }
    }
}

// ---------------------------------------------------------------------------
// gemm_big v2: 256x128 tile (8 M-frag x 4 N-frag per wave = 32 MFMA per
// barrier window), BK=32, 3-buffer counted-vmcnt (6 loads/stage -> vmcnt(6)).
// Grid (250, 8) = 2000 blocks; LDS 3*(16K+8K) = 72 KB -> 2 blocks/CU.
// Logits GEMM only (f32 out).
// ---------------------------------------------------------------------------
__global__ __launch_bounds__(256) void gemm_big(
    const u16* __restrict__ A, int lda,
    const u16* __restrict__ B, int ldb,
    float* Cf, int ldc,
    const float* __restrict__ bias, int K)
{
    __shared__ u16 As[3][8192];   // 256 rows x 32 k
    __shared__ u16 Bs[3][4096];   // 128 rows x 32 k
    int mt, nt; swz_tile(mt, nt);
    const int m0 = mt << 8, n0 = nt << 7;
    const int t = threadIdx.x, lane = t & 63, wave = t >> 6;
    const int wr = (wave >> 1) << 7, wc = (wave & 1) << 6;
    const int fr = lane & 15, fq = lane >> 4;
    const int srow = t >> 2;
    const int sch  = (t & 3) ^ ((srow >> 1) & 3);
    const u16* Ag = A + (long)(m0 + srow) * lda + (sch << 3);
    const u16* Bg = B + (long)(n0 + srow) * ldb + (sch << 3);

    f32x4 acc[8][4];
    #pragma unroll
    for (int i = 0; i < 8; i++)
        #pragma unroll
        for (int j = 0; j < 4; j++) acc[i][j] = (f32x4){0.f, 0.f, 0.f, 0.f};

    const int nk = K >> 5;
    auto stage = [&](int ki, int buf) {
        const int ko = ki << 5;
        gl_lds16(Ag + ko,             &As[buf][t << 3]);
        gl_lds16(Ag + 64L * lda + ko, &As[buf][2048 + (t << 3)]);
        gl_lds16(Ag + 128L * lda + ko, &As[buf][4096 + (t << 3)]);
        gl_lds16(Ag + 192L * lda + ko, &As[buf][6144 + (t << 3)]);
        gl_lds16(Bg + ko,             &Bs[buf][t << 3]);
        gl_lds16(Bg + 64L * ldb + ko, &Bs[buf][2048 + (t << 3)]);
    };
    stage(0, 0);
    if (nk > 1) { stage(1, 1); SYNC_VM(6); }
    else        { SYNC_VM(0); }

    int cur = 0;
    for (int ki = 0; ki < nk; ki++) {
        const bool st = (ki + 2 < nk);
        if (st) stage(ki + 2, cur == 0 ? 2 : cur - 1);
        short8 af[8], bf[4];
        #pragma unroll
        for (int i = 0; i < 8; i++) {
            const int r = wr + (i << 4) + fr;
            af[i] = *(const short8*)&As[cur][(r << 5) + ((fq ^ ((r >> 1) & 3)) << 3)];
        }
        #pragma unroll
        for (int j = 0; j < 4; j++) {
            const int c = wc + (j << 4) + fr;
            bf[j] = *(const short8*)&Bs[cur][(c << 5) + ((fq ^ ((c >> 1) & 3)) << 3)];
        }
        #pragma unroll
        for (int i = 0; i < 8; i++)
            #pragma unroll
            for (int j = 0; j < 4; j++)
                acc[i][j] = __builtin_amdgcn_mfma_f32_16x16x32_bf16(af[i], bf[j], acc[i][j], 0, 0, 0);
        if (ki + 1 < nk) {
            if (st) SYNC_VM(6);
            else    SYNC_VM(0);
        }
        cur = (cur == 2) ? 0 : cur + 1;
    }

    #pragma unroll
    for (int i = 0; i < 8; i++) {
        #pragma unroll
        for (int j = 0; j < 4; j++) {
            const int nl  = n0 + wc + (j << 4) + fr;
            const int mlb = m0 + wr + (i << 4) + (fq << 2);
            const float bsv = bias ? bias[nl] : 0.f;
            #pragma unroll
            for (int r = 0; r < 4; r++)
                Cf[(long)(mlb + r) * ldc + nl] = acc[i][j][r] + bsv;
        }
    }
}

// ---------------------------------------------------------------------------
// Fused attention v2 (KV-split-2, R12-proven): block per (q-tile 32, head,
// batch), 4 waves = {2 q-halves x 2 kv-halves}; flash combine via LDS.
// ---------------------------------------------------------------------------
__global__ __launch_bounds__(256) void attn_fused(
    const u16* __restrict__ qkb, const u16* __restrict__ kb_, int ldk,
    const u16* __restrict__ vt,
    const int* __restrict__ ids, u16* __restrict__ attc, int causal)
{
    __shared__ u16 Ks[2][4096];      // [kv-half][64 keys x 64 d]
    __shared__ u16 Vs[2][4096];      // [kv-half][64 d x 64 s]
    __shared__ short Ps[4][16][72];
    const int t = threadIdx.x, lane = t & 63, w = t >> 6;
    const int fr = lane & 15, fq = lane >> 4;
    const int qh = w & 1, kvh = w >> 1;
    const int q0 = blockIdx.x << 5, h = blockIdx.y, b = blockIdx.z;

    const u16* qp = qkb + (long)(b * 512 + q0 + (qh << 4) + fr) * 1024 + h * 64 + (fq << 3);
    short8 aq0 = *(const short8*)qp;
    short8 aq1 = *(const short8*)(qp + 32);

    const int sr = t >> 3, sc = (t & 7) ^ (sr & 7);
    const u16* kg0 = kb_ + (long)(b * 512 + sr) * ldk + h * 64 + (sc << 3);
    const u16* kg1 = kg0 + 32L * ldk;
    const u16* vg0 = vt + (long)b * S2W + (long)(h * 64 + sr) * 512 + (sc << 3);
    const u16* vg1 = vg0 + 32L * 512;

    unsigned pmask = 0;
    #pragma unroll
    for (int kt = 0; kt < 8; kt++)
        #pragma unroll
        for (int j = 0; j < 4; j++)
            if (ids[b * 512 + (kt << 6) + (j << 4) + fr] == PADID)
                pmask |= 1u << ((kt << 2) + j);

    const int nkt = causal ? (((q0 + 31) >> 6) + 1) : 8;
    const int nA = (nkt + 1) >> 1, nB = nkt - nA;
    const int myn = kvh ? nB : nA;

    float m[4], l[4]; f32x4 oc[4];
    #pragma unroll
    for (int r = 0; r < 4; r++) { m[r] = -INFINITY; l[r] = 0.f; oc[r] = (f32x4){0.f,0.f,0.f,0.f}; }

    for (int i = 0; i < nA; i++) {
        {
            const long soA = (long)(i << 6);
            gl_lds16(kg0 + soA * ldk, &Ks[0][t << 3]);
            gl_lds16(kg1 + soA * ldk, &Ks[0][(t + 256) << 3]);
            gl_lds16(vg0 + soA,       &Vs[0][t << 3]);
            gl_lds16(vg1 + soA,       &Vs[0][(t + 256) << 3]);
            if (i < nB) {
                const long soB = (long)((nA + i) << 6);
                gl_lds16(kg0 + soB * ldk, &Ks[1][t << 3]);
                gl_lds16(kg1 + soB * ldk, &Ks[1][(t + 256) << 3]);
                gl_lds16(vg0 + soB,       &Vs[1][t << 3]);
                gl_lds16(vg1 + soB,       &Vs[1][(t + 256) << 3]);
            }
        }
        __syncthreads();

        if (i < myn) {
            const int kt = (kvh ? nA : 0) + i;
            f32x4 sc4[4];
            #pragma unroll
            for (int j = 0; j < 4; j++) sc4[j] = (f32x4){0.f,0.f,0.f,0.f};
            #pragma unroll
            for (int j = 0; j < 4; j++) {
                const int rr = (j << 4) + fr;
                short8 bk0 = *(const short8*)&Ks[kvh][rr * 64 + ((fq ^ (rr & 7)) << 3)];
                short8 bk1 = *(const short8*)&Ks[kvh][rr * 64 + (((fq | 4) ^ (rr & 7)) << 3)];
                sc4[j] = __builtin_amdgcn_mfma_f32_16x16x32_bf16(aq0, bk0, sc4[j], 0, 0, 0);
                sc4[j] = __builtin_amdgcn_mfma_f32_16x16x32_bf16(aq1, bk1, sc4[j], 0, 0, 0);
            }
            const int s0 = kt << 6;
            #pragma unroll
            for (int r = 0; r < 4; r++) {
                const int qa = q0 + (qh << 4) + (fq << 2) + r;
                float mx = -INFINITY;
                #pragma unroll
                for (int j = 0; j < 4; j++) {
                    bool msk = ((pmask >> ((kt << 2) + j)) & 1) ||
                               (causal && (s0 + (j << 4) + fr) > qa);
                    float sv = msk ? -INFINITY : sc4[j][r] * 0.125f;
                    sc4[j][r] = sv;
                    mx = fmaxf(mx, sv);
                }
                mx = fmaxf(mx, __shfl_xor(mx, 1)); mx = fmaxf(mx, __shfl_xor(mx, 2));
                mx = fmaxf(mx, __shfl_xor(mx, 4)); mx = fmaxf(mx, __shfl_xor(mx, 8));
                float mnew  = fmaxf(m[r], mx);
                float scale = (mnew == -INFINITY) ? 1.f : __expf(m[r] - mnew);
                float ps = 0.f;
                #pragma unroll
                for (int j = 0; j < 4; j++) {
                    float p2 = (sc4[j][r] == -INFINITY) ? 0.f : __expf(sc4[j][r] - mnew);
                    sc4[j][r] = p2; ps += p2;
                }
                ps += __shfl_xor(ps, 1); ps += __shfl_xor(ps, 2);
                ps += __shfl_xor(ps, 4); ps += __shfl_xor(ps, 8);
                l[r] = l[r] * scale + ps;
                m[r] = mnew;
                #pragma unroll
                for (int j2 = 0; j2 < 4; j2++) oc[j2][r] *= scale;
            }
            #pragma unroll
            for (int r = 0; r < 4; r++)
                #pragma unroll
                for (int j = 0; j < 4; j++)
                    Ps[w][(fq << 2) + r][(j << 4) + fr] = (short)f2bf(sc4[j][r]);
            #pragma unroll
            for (int kc2 = 0; kc2 < 2; kc2++) {
                short8 pa = *(const short8*)&Ps[w][fr][(kc2 << 5) + (fq << 3)];
                #pragma unroll
                for (int j2 = 0; j2 < 4; j2++) {
                    const int rd = (j2 << 4) + fr;
                    const int cch = (((kc2 << 2) | fq) ^ (rd & 7));
                    short8 bv = *(const short8*)&Vs[kvh][rd * 64 + (cch << 3)];
                    oc[j2] = __builtin_amdgcn_mfma_f32_16x16x32_bf16(pa, bv, oc[j2], 0, 0, 0);
                }
            }
        }
        __syncthreads();
    }

    // ---- combine kv halves (reuse Ks/Vs LDS) ----
    float* Ob = (float*)&Ks[0][0];
    float* Ml = (float*)&Vs[0][0];
    if (kvh == 1) {
        #pragma unroll
        for (int r = 0; r < 4; r++) {
            const int row = (qh << 4) + (fq << 2) + r;
            Ml[(row << 1)]     = m[r];
            Ml[(row << 1) + 1] = l[r];
            #pragma unroll
            for (int j2 = 0; j2 < 4; j2++)
                Ob[(row << 6) + (j2 << 4) + fr] = oc[j2][r];
        }
    }
    __syncthreads();
    if (kvh == 0) {
        #pragma unroll
        for (int r = 0; r < 4; r++) {
            const int row = (qh << 4) + (fq << 2) + r;
            const float mB = Ml[(row << 1)], lB = Ml[(row << 1) + 1];
            const float mN = fmaxf(m[r], mB);
            float sA, sB;
            if (mN == -INFINITY) { sA = 0.f; sB = 0.f; }
            else {
                sA = (m[r] == -INFINITY) ? 0.f : __expf(m[r] - mN);
                sB = (mB   == -INFINITY) ? 0.f : __expf(mB   - mN);
            }
            const float L = l[r] * sA + lB * sB;
            const float inv = (L > 0.f) ? 1.f / L : 0.f;
            #pragma unroll
            for (int j2 = 0; j2 < 4; j2++) {
                float val = (oc[j2][r] * sA + Ob[(row << 6) + (j2 << 4) + fr] * sB) * inv;
                attc[(long)(b * 512 + q0 + (qh << 4) + (fq << 2) + r) * 512 +
                     h * 64 + (j2 << 4) + fr] = f2bf(val);
            }
        }
    }
}

// LayerNorm over D=512: 4 rows/block (wave per row). f32 in -> bf16 out.
__global__ __launch_bounds__(256) void ln_rows(
    const float* __restrict__ x, const float* __restrict__ g,
    const float* __restrict__ b, u16* __restrict__ out)
{
    int row  = blockIdx.x * 4 + (threadIdx.x >> 6);
    int lane = threadIdx.x & 63;
    const float* xr = x + (long)row * Dm;
    float v[8]; float s = 0.f;
    #pragma unroll
    for (int i = 0; i < 8; i++) { v[i] = xr[lane + (i << 6)]; s += v[i]; }
    #pragma unroll
    for (int o = 32; o > 0; o >>= 1) s += __shfl_xor(s, o);
    float mean = s * (1.f / 512.f);
    float q = 0.f;
    #pragma unroll
    for (int i = 0; i < 8; i++) { float d = v[i] - mean; q += d * d; }
    #pragma unroll
    for (int o = 32; o > 0; o >>= 1) q += __shfl_xor(q, o);
    float rinv = rsqrtf(q * (1.f / 512.f) + LNEPS);
    u16* orow = out + (long)row * Dm;
    #pragma unroll
    for (int i = 0; i < 8; i++) {
        int c = lane + (i << 6);
        orow[c] = f2bf((v[i] - mean) * rinv * g[c] + b[c]);
    }
}

// x[b,s,:] = embed[id]*sqrt(D) + PE(s,:)   (f32 in/out)
__global__ __launch_bounds__(256) void embed_pe(
    const int* __restrict__ ids, const float* __restrict__ emb,
    float* __restrict__ out)
{
    int idx = blockIdx.x * 256 + threadIdx.x;   // NTOK*512 = 2^20
    int d   = idx & 511;
    int tok = idx >> 9;
    int s   = tok & 511;
    int id  = ids[tok];
    float val = emb[(long)id * Dm + d] * 22.62741699796952f;     // sqrt(512)
    int i2 = d >> 1;
    float dv  = expf((float)(i2 << 1) * (-9.210340371976184f / 512.f));
    float ang = (float)s * dv;
    val += (d & 1) ? cosf(ang) : sinf(ang);
    out[idx] = val;
}

// ---------------------------------------------------------------------------
extern "C" void kernel_launch(void* const* d_in, const int* in_sizes, int n_in,
                              void* d_out, int out_size, void* d_ws, size_t ws_size,
                              hipStream_t stream)
{
    (void)in_sizes; (void)n_in; (void)out_size; (void)ws_size;
    const int*   src       = (const int*)d_in[0];
    const int*   tgt       = (const int*)d_in[1];
    const float* src_embed = (const float*)d_in[2];
    const float* tgt_embed = (const float*)d_in[3];
    const float* enc_b1  = (const float*)d_in[9];
    const float* enc_b2  = (const float*)d_in[11];
    const float* enc_ln1g = (const float*)d_in[12];
    const float* enc_ln1b = (const float*)d_in[13];
    const float* enc_ln2g = (const float*)d_in[14];
    const float* enc_ln2b = (const float*)d_in[15];
    const float* enc_lnfg = (const float*)d_in[16];
    const float* enc_lnfb = (const float*)d_in[17];
    const float* dec_b1  = (const float*)d_in[27];
    const float* dec_b2  = (const float*)d_in[29];
    const float* dec_ln1g = (const float*)d_in[30];
    const float* dec_ln1b = (const float*)d_in[31];
    const float* dec_ln2g = (const float*)d_in[32];
    const float* dec_ln2b = (const float*)d_in[33];
    const float* dec_ln3g = (const float*)d_in[34];
    const float* dec_ln3b = (const float*)d_in[35];
    const float* dec_lnfg = (const float*)d_in[36];
    const float* dec_lnfb = (const float*)d_in[37];
    const float* out_b  = (const float*)d_in[39];

    char* wp = (char*)d_ws;
    auto carve = [&](size_t nbytes) {
        void* p = (void*)wp; wp += (nbytes + 255) & ~(size_t)255; return p;
    };

    const long nW = (long)NLay * S2W;
    const long nF = (long)NLay * DFFm * Dm;
    const long nO = 32000L * Dm;

    u16* Wb[12];
    for (int i = 0; i < 12; i++) Wb[i] = (u16*)carve((size_t)nW * 2);
    u16* w1E  = (u16*)carve((size_t)nF * 2);
    u16* w2E  = (u16*)carve((size_t)nF * 2);
    u16* w1D  = (u16*)carve((size_t)nF * 2);
    u16* w2D  = (u16*)carve((size_t)nF * 2);
    u16* outW = (u16*)carve((size_t)nO * 2);

    float* x  = (float*)carve((size_t)NTOK * Dm * 4);
    float* y  = (float*)carve((size_t)NTOK * Dm * 4);
    u16* nrm  = (u16*)carve((size_t)NTOK * Dm * 2);
    u16* qkb  = (u16*)carve((size_t)NTOK * 1024 * 2);
    u16* vt   = (u16*)carve((size_t)Bb * Dm * 512 * 2);
    u16* attc = (u16*)carve((size_t)NTOK * Dm * 2);
    u16* h1   = (u16*)carve((size_t)NTOK * DFFm * 2);
    u16* memn = (u16*)carve((size_t)NTOK * Dm * 2);
    u16* kc6  = (u16*)carve((size_t)NLay * NTOK * 512 * 2);   // cross K, per layer
    u16* vt6  = (u16*)carve((size_t)NLay * Bb * S2W * 2);     // cross V^T, per layer

    const int wi[12] = {4, 5, 6, 7, 18, 19, 20, 21, 22, 23, 24, 25};
    CvtJobs jobs;
    for (int i = 0; i < 12; i++) {
        jobs.s[i] = (const float*)d_in[wi[i]]; jobs.d[i] = Wb[i]; jobs.n4[i] = nW >> 2;
    }
    jobs.s[12] = (const float*)d_in[8];  jobs.d[12] = w1E;  jobs.n4[12] = nF >> 2;
    jobs.s[13] = (const float*)d_in[10]; jobs.d[13] = w2E;  jobs.n4[13] = nF >> 2;
    jobs.s[14] = (const float*)d_in[26]; jobs.d[14] = w1D;  jobs.n4[14] = nF >> 2;
    jobs.s[15] = (const float*)d_in[28]; jobs.d[15] = w2D;  jobs.n4[15] = nF >> 2;
    jobs.s[16] = (const float*)d_in[38]; jobs.d[16] = outW; jobs.n4[16] = nO >> 2;
    cvt_many<<<dim3(512, 17), 256, 0, stream>>>(jobs);

    const int BIG = 1 << 28;
    u16 *eWq = Wb[0], *eWk = Wb[1], *eWv = Wb[2], *eWo = Wb[3];
    u16 *sWq = Wb[4], *sWk = Wb[5], *sWv = Wb[6], *sWo = Wb[7];
    u16 *cWq = Wb[8], *cWk = Wb[9], *cWv = Wb[10], *cWo = Wb[11];

    // ---------------- Encoder ----------------
    embed_pe<<<4096, 256, 0, stream>>>(src, src_embed, x);
    for (int l = 0; l < NLay; l++) {
        const size_t wo = (size_t)l * S2W;
        ln_rows<<<512, 256, 0, stream>>>(x, enc_ln1g + l * Dm, enc_ln1b + l * Dm, nrm);
        gemm_bt<<<dim3(24, 32, 1), 256, 0, stream>>>(nrm, nrm, nrm, 512,
            eWq + wo, eWk + wo, eWv + wo, 512,
            nullptr, qkb, 1024, nullptr, 0, 512, 1, 1024, 0, vt);
        attn_fused<<<dim3(16, Hh, Bb), 256, 0, stream>>>(qkb, qkb + 512, 1024, vt, src, attc, 0);
        gemm_bt<<<dim3(8, 32, 2), 256, 0, stream>>>(attc, attc, attc, 512,
            eWo + wo, nullptr, nullptr, 512,
            x, nullptr, 512, nullptr, 0, 256, 2, BIG, 0, nullptr);
        ln_rows<<<512, 256, 0, stream>>>(x, enc_ln2g + l * Dm, enc_ln2b + l * Dm, nrm);
        gemm_bt<<<dim3(32, 32, 1), 256, 0, stream>>>(nrm, nrm, nrm, 512,
            w1E + (size_t)l * DFFm * Dm, nullptr, nullptr, 512,
            nullptr, h1, DFFm, enc_b1 + l * DFFm, 1, 512, 1, BIG, 0, nullptr);
        gemm_bt<<<dim3(8, 32, 4), 256, 0, stream>>>(h1, h1, h1, DFFm,
            w2E + (size_t)l * Dm * DFFm, nullptr, nullptr, DFFm,
            x, nullptr, 512, enc_b2 + l * Dm, 0, 512, 4, BIG, 0, nullptr);
    }
    ln_rows<<<512, 256, 0, stream>>>(x, enc_lnfg, enc_lnfb, memn);
    gemm_kv6<<<dim3(16, 32, NLay), 256, 0, stream>>>(memn, cWk, cWv, kc6, vt6);

    // ---------------- Decoder ----------------
    embed_pe<<<4096, 256, 0, stream>>>(tgt, tgt_embed, y);
    for (int l = 0; l < NLay; l++) {
        const size_t wo = (size_t)l * S2W;
        // self-attention (causal + tgt pad)
        ln_rows<<<512, 256, 0, stream>>>(y, dec_ln1g + l * Dm, dec_ln1b + l * Dm, nrm);
        gemm_bt<<<dim3(24, 32, 1), 256, 0, stream>>>(nrm, nrm, nrm, 512,
            sWq + wo, sWk + wo, sWv + wo, 512,
            nullptr, qkb, 1024, nullptr, 0, 512, 1, 1024, 0, vt);
        attn_fused<<<dim3(16, Hh, Bb), 256, 0, stream>>>(qkb, qkb + 512, 1024, vt, tgt, attc, 1);
        gemm_bt<<<dim3(8, 32, 2), 256, 0, stream>>>(attc, attc, attc, 512,
            sWo + wo, nullptr, nullptr, 512,
            y, nullptr, 512, nullptr, 0, 256, 2, BIG, 0, nullptr);
        // cross-attention: Q only (K/V precomputed by gemm_kv6)
        ln_rows<<<512, 256, 0, stream>>>(y, dec_ln2g + l * Dm, dec_ln2b + l * Dm, nrm);
        gemm_bt<<<dim3(8, 32, 1), 256, 0, stream>>>(nrm, nrm, nrm, 512,
            cWq + wo, nullptr, nullptr, 512,
            nullptr, qkb, 1024, nullptr, 0, 512, 1, BIG, 0, nullptr);
        attn_fused<<<dim3(16, Hh, Bb), 256, 0, stream>>>(qkb,
            kc6 + (size_t)l * NTOK * 512, 512, vt6 + (size_t)l * Bb * S2W, src, attc, 0);
        gemm_bt<<<dim3(8, 32, 2), 256, 0, stream>>>(attc, attc, attc, 512,
            cWo + wo, nullptr, nullptr, 512,
            y, nullptr, 512, nullptr, 0, 256, 2, BIG, 0, nullptr);
        // FFN
        ln_rows<<<512, 256, 0, stream>>>(y, dec_ln3g + l * Dm, dec_ln3b + l * Dm, nrm);
        gemm_bt<<<dim3(32, 32, 1), 256, 0, stream>>>(nrm, nrm, nrm, 512,
            w1D + (size_t)l * DFFm * Dm, nullptr, nullptr, 512,
            nullptr, h1, DFFm, dec_b1 + l * DFFm, 1, 512, 1, BIG, 0, nullptr);
        gemm_bt<<<dim3(8, 32, 4), 256, 0, stream>>>(h1, h1, h1, DFFm,
            w2D + (size_t)l * Dm * DFFm, nullptr, nullptr, DFFm,
            y, nullptr, 512, dec_b2 + l * Dm, 0, 512, 4, BIG, 0, nullptr);
    }
    ln_rows<<<512, 256, 0, stream>>>(y, dec_lnfg, dec_lnfb, nrm);

    // final projection to vocab: [2048][32000] f32 out, 256x128 tiles
    gemm_big<<<dim3(250, 8), 256, 0, stream>>>(nrm, 512, outW, 512,
        (float*)d_out, 32000, out_b, 512);
}

// Round 15
// 1568.831 us; speedup vs baseline: 1.0518x; 1.0397x over previous
//
#include <hip/hip_runtime.h>
#include <hip/hip_bf16.h>
#include <math.h>

// ---------------- problem constants ----------------
#define Dm    512
#define Hh    8
#define NLay  6
#define DFFm  2048
#define Bb    4
#define NTOK  2048          // B * S
#define PADID 1
#define LNEPS 1e-5f
#define S2W   262144        // 512*512 elements

typedef __attribute__((ext_vector_type(8))) short short8;   // 8 x bf16
typedef __attribute__((ext_vector_type(4))) float f32x4;
typedef unsigned short u16;

__device__ __forceinline__ u16 f2bf(float f) {
    union { float f; unsigned int i; } x; x.f = f;
    unsigned int r = x.i + 0x7fffu + ((x.i >> 16) & 1u);   // RNE
    return (u16)(r >> 16);
}

// async global->LDS, 16B per lane (dest linear-in-lane: base+lane*16)
typedef const __attribute__((address_space(1))) void* as1cv;
typedef __attribute__((address_space(3))) void* as3v;
__device__ __forceinline__ void gl_lds16(const u16* g, u16* l) {
    __builtin_amdgcn_global_load_lds((as1cv)g, (as3v)l, 16, 0, 0);
}

// counted-vmcnt sync (T3/T4) — used in gemm_big only
#define SYNC_VM(N) do { \
    asm volatile("s_waitcnt vmcnt(" #N ")" ::: "memory"); \
    __builtin_amdgcn_s_barrier(); \
    __builtin_amdgcn_sched_barrier(0); \
} while (0)

// bijective XCD-chunk swizzle (m204), M fastest within an XCD's chunk.
__device__ __forceinline__ void swz_tile(int& mt, int& nt) {
    const int nwg  = gridDim.x * gridDim.y;
    const int orig = blockIdx.y * gridDim.x + blockIdx.x;
    const int q8 = nwg >> 3, r8 = nwg & 7;
    const int xcd = orig & 7, idx = orig >> 3;
    const int wgid = (xcd < r8 ? xcd * (q8 + 1) : r8 * (q8 + 1) + (xcd - r8) * q8) + idx;
    const int MT = gridDim.y;
    mt = wgid % MT;
    nt = wgid / MT;
}

// ---- one-launch f32->bf16 conversion of all 17 weight tensors ----
struct CvtJobs {
    const float* s[17];
    u16*         d[17];
    long         n4[17];
};
__global__ __launch_bounds__(256) void cvt_many(CvtJobs j) {
    const int job = blockIdx.y;
    const long n4 = j.n4[job];
    const float* in = j.s[job];
    u16* out = j.d[job];
    long i = (long)blockIdx.x * 256 + threadIdx.x;
    const long stride = (long)gridDim.x * 256;
    for (; i < n4; i += stride) {
        float4 v = ((const float4*)in)[i];
        ushort4 o;
        o.x = f2bf(v.x); o.y = f2bf(v.y); o.z = f2bf(v.z); o.w = f2bf(v.w);
        ((ushort4*)out)[i] = o;
    }
}

// ---------------------------------------------------------------------------
// gemm_bt (R12-proven): 64x64 tile, BK=64, dbuf, one barrier per K-step.
// Per-512-col part p = n0>>9 selects (A0..A2, B0..B2); if B1==nullptr, B is
// contiguous and n indexes B0. Split-K: grid.z slices of Kc; ns>1 ->
// unsafeAtomicAdd f32 into Cf (bias from z==0 only).
// ns==1 epilogue: nl >= vth -> vt[b][nl-vth][s]; else C[ml*csm + nl + koff].
// ---------------------------------------------------------------------------
__global__ __launch_bounds__(256) void gemm_bt(
    const u16* __restrict__ A0, const u16* __restrict__ A1,
    const u16* __restrict__ A2, int lda,
    const u16* __restrict__ B0, const u16* __restrict__ B1,
    const u16* __restrict__ B2, int ldb,
    float* Cf, u16* Cb, int csm,
    const float* __restrict__ bias, int relu,
    int Kc, int ns, int vth, int koff, u16* vtp)
{
    __shared__ u16 As[2][4096];   // 64 rows x 64 k
    __shared__ u16 Bs[2][4096];
    int mt, nt; swz_tile(mt, nt);
    const int m0 = mt << 6, n0 = nt << 6;
    const int t = threadIdx.x, lane = t & 63, wave = t >> 6;
    const int wr = (wave >> 1) << 5, wc = (wave & 1) << 5;
    const int fr = lane & 15, fq = lane >> 4;
    const int srow = t >> 3;
    const int sch  = (t & 7) ^ (srow & 7);

    const int p = n0 >> 9;
    const u16* Amat = (p == 0) ? A0 : (p == 1 ? A1 : A2);
    const u16* Bmat; int nb;
    if (B1) { Bmat = (p == 0) ? B0 : (p == 1 ? B1 : B2); nb = n0 & 511; }
    else    { Bmat = B0; nb = n0; }
    const long kb = (long)blockIdx.z * Kc;

    const u16* Ag0 = Amat + (long)(m0 + srow) * lda + kb + (sch << 3);
    const u16* Ag1 = Ag0 + 32L * lda;
    const u16* Bg0 = Bmat + (long)(nb + srow) * ldb + kb + (sch << 3);
    const u16* Bg1 = Bg0 + 32L * ldb;

    f32x4 acc[2][2];
    #pragma unroll
    for (int i = 0; i < 2; i++)
        #pragma unroll
        for (int j = 0; j < 2; j++) acc[i][j] = (f32x4){0.f, 0.f, 0.f, 0.f};

    const int nk = Kc >> 6;
    gl_lds16(Ag0, &As[0][t << 3]);
    gl_lds16(Ag1, &As[0][(t + 256) << 3]);
    gl_lds16(Bg0, &Bs[0][t << 3]);
    gl_lds16(Bg1, &Bs[0][(t + 256) << 3]);
    __syncthreads();
    for (int ki = 0; ki < nk; ki++) {
        const int cur = ki & 1;
        if (ki + 1 < nk) {
            const int ko = (ki + 1) << 6;
            gl_lds16(Ag0 + ko, &As[cur ^ 1][t << 3]);
            gl_lds16(Ag1 + ko, &As[cur ^ 1][(t + 256) << 3]);
            gl_lds16(Bg0 + ko, &Bs[cur ^ 1][t << 3]);
            gl_lds16(Bg1 + ko, &Bs[cur ^ 1][(t + 256) << 3]);
        }
        const int r0 = wr + fr, r1 = wr + 16 + fr;
        const int c0 = wc + fr, c1 = wc + 16 + fr;
        #pragma unroll
        for (int h = 0; h < 2; h++) {
            const int lc = fq | (h << 2);
            short8 af0 = *(const short8*)&As[cur][(r0 << 6) + ((lc ^ (r0 & 7)) << 3)];
            short8 af1 = *(const short8*)&As[cur][(r1 << 6) + ((lc ^ (r1 & 7)) << 3)];
            short8 bf0 = *(const short8*)&Bs[cur][(c0 << 6) + ((lc ^ (c0 & 7)) << 3)];
            short8 bf1 = *(const short8*)&Bs[cur][(c1 << 6) + ((lc ^ (c1 & 7)) << 3)];
            acc[0][0] = __builtin_amdgcn_mfma_f32_16x16x32_bf16(af0, bf0, acc[0][0], 0, 0, 0);
            acc[0][1] = __builtin_amdgcn_mfma_f32_16x16x32_bf16(af0, bf1, acc[0][1], 0, 0, 0);
            acc[1][0] = __builtin_amdgcn_mfma_f32_16x16x32_bf16(af1, bf0, acc[1][0], 0, 0, 0);
            acc[1][1] = __builtin_amdgcn_mfma_f32_16x16x32_bf16(af1, bf1, acc[1][1], 0, 0, 0);
        }
        __syncthreads();
    }

    #pragma unroll
    for (int i = 0; i < 2; i++) {
        #pragma unroll
        for (int j = 0; j < 2; j++) {
            const int nl  = n0 + wc + (j << 4) + fr;
            const int mlb = m0 + wr + (i << 4) + (fq << 2);
            const float bsv = bias ? bias[nl] : 0.f;
            #pragma unroll
            for (int r = 0; r < 4; r++) {
                const int ml = mlb + r;
                if (ns > 1) {
                    float v = acc[i][j][r] + (blockIdx.z == 0 ? bsv : 0.f);
                    unsafeAtomicAdd(&Cf[(long)ml * csm + nl + koff], v);
                } else {
                    float v = acc[i][j][r] + bsv;
                    if (nl >= vth) {
                        vtp[(long)(ml >> 9) * S2W + (long)(nl - vth) * 512 + (ml & 511)] = f2bf(v);
                    } else {
                        if (relu) v = fmaxf(v, 0.f);
                        long ci = (long)ml * csm + nl + koff;
                        if (Cf) Cf[ci] = v;
                        if (Cb) Cb[ci] = f2bf(v);
                    }
                }
            }
        }
    }
}

// ---------------------------------------------------------------------------
// gemm_kv6 (R12-proven): all 6 decoder cross K/V projections in one dispatch.
// ---------------------------------------------------------------------------
__global__ __launch_bounds__(256) void gemm_kv6(
    const u16* __restrict__ A,
    const u16* __restrict__ Wk, const u16* __restrict__ Wv,
    u16* __restrict__ kc, u16* __restrict__ vtc)
{
    __shared__ u16 As[2][4096];
    __shared__ u16 Bs[2][4096];
    int mt, nt; swz_tile(mt, nt);
    const int m0 = mt << 6, n0 = nt << 6;
    const int z = blockIdx.z;
    const int t = threadIdx.x, lane = t & 63, wave = t >> 6;
    const int wr = (wave >> 1) << 5, wc = (wave & 1) << 5;
    const int fr = lane & 15, fq = lane >> 4;
    const int srow = t >> 3;
    const int sch  = (t & 7) ^ (srow & 7);

    const int p = n0 >> 9;
    const u16* Bmat = ((p == 0) ? Wk : Wv) + (size_t)z * S2W;
    const int nb = n0 & 511;

    const u16* Ag0 = A + (long)(m0 + srow) * 512 + (sch << 3);
    const u16* Ag1 = Ag0 + 32L * 512;
    const u16* Bg0 = Bmat + (long)(nb + srow) * 512 + (sch << 3);
    const u16* Bg1 = Bg0 + 32L * 512;

    f32x4 acc[2][2];
    #pragma unroll
    for (int i = 0; i < 2; i++)
        #pragma unroll
        for (int j = 0; j < 2; j++) acc[i][j] = (f32x4){0.f, 0.f, 0.f, 0.f};

    gl_lds16(Ag0, &As[0][t << 3]);
    gl_lds16(Ag1, &As[0][(t + 256) << 3]);
    gl_lds16(Bg0, &Bs[0][t << 3]);
    gl_lds16(Bg1, &Bs[0][(t + 256) << 3]);
    __syncthreads();
    for (int ki = 0; ki < 8; ki++) {
        const int cur = ki & 1;
        if (ki + 1 < 8) {
            const int ko = (ki + 1) << 6;
            gl_lds16(Ag0 + ko, &As[cur ^ 1][t << 3]);
            gl_lds16(Ag1 + ko, &As[cur ^ 1][(t + 256) << 3]);
            gl_lds16(Bg0 + ko, &Bs[cur ^ 1][t << 3]);
            gl_lds16(Bg1 + ko, &Bs[cur ^ 1][(t + 256) << 3]);
        }
        const int r0 = wr + fr, r1 = wr + 16 + fr;
        const int c0 = wc + fr, c1 = wc + 16 + fr;
        #pragma unroll
        for (int h = 0; h < 2; h++) {
            const int lc = fq | (h << 2);
            short8 af0 = *(const short8*)&As[cur][(r0 << 6) + ((lc ^ (r0 & 7)) << 3)];
            short8 af1 = *(const short8*)&As[cur][(r1 << 6) + ((lc ^ (r1 & 7)) << 3)];
            short8 bf0 = *(const short8*)&Bs[cur][(c0 << 6) + ((lc ^ (c0 & 7)) << 3)];
            short8 bf1 = *(const short8*)&Bs[cur][(c1 << 6) + ((lc ^ (c1 & 7)) << 3)];
            acc[0][0] = __builtin_amdgcn_mfma_f32_16x16x32_bf16(af0, bf0, acc[0][0], 0, 0, 0);
            acc[0][1] = __builtin_amdgcn_mfma_f32_16x16x32_bf16(af0, bf1, acc[0][1], 0, 0, 0);
            acc[1][0] = __builtin_amdgcn_mfma_f32_16x16x32_bf16(af1, bf0, acc[1][0], 0, 0, 0);
            acc[1][1] = __builtin_amdgcn_mfma_f32_16x16x32_bf16(af1, bf1, acc[1][1], 0, 0, 0);
        }
        __syncthreads();
    }

    #pragma unroll
    for (int i = 0; i < 2; i++) {
        #pragma unroll
        for (int j = 0; j < 2; j++) {
            const int nl  = n0 + wc + (j << 4) + fr;
            const int mlb = m0 + wr + (i << 4) + (fq << 2);
            #pragma unroll
            for (int r = 0; r < 4; r++) {
                const int ml = mlb + r;
                const u16 v = f2bf(acc[i][j][r]);
                if (nl < 512)
                    kc[(long)z * NTOK * 512 + (long)ml * 512 + nl] = v;
                else
                    vtc[(long)z * Bb * S2W + (long)(ml >> 9) * S2W +
                        (long)(nl - 512) * 512 + (ml & 511)] = v;
            }
        }
    }
}

// ---------------------------------------------------------------------------
// gemm_big (R12-proven): 128x128 tile, BK=32, 3-buffer counted-vmcnt.
// Logits GEMM only (f32 out).
// ---------------------------------------------------------------------------
__global__ __launch_bounds__(256) void gemm_big(
    const u16* __restrict__ A, int lda,
    const u16* __restrict__ B, int ldb,
    float* Cf, int ldc,
    const float* __restrict__ bias, int K)
{
    __shared__ u16 As[3][4096];
    __shared__ u16 Bs[3][4096];
    int mt, nt; swz_tile(mt, nt);
    const int m0 = mt << 7, n0 = nt << 7;
    const int t = threadIdx.x, lane = t & 63, wave = t >> 6;
    const int wr = (wave >> 1) << 6, wc = (wave & 1) << 6;
    const int fr = lane & 15, fq = lane >> 4;
    const int srow = t >> 2;
    const int sch  = (t & 3) ^ ((srow >> 1) & 3);
    const u16* Ag0 = A + (long)(m0 + srow) * lda + (sch << 3);
    const u16* Ag1 = A + (long)(m0 + 64 + srow) * lda + (sch << 3);
    const u16* Bg0 = B + (long)(n0 + srow) * ldb + (sch << 3);
    const u16* Bg1 = B + (long)(n0 + 64 + srow) * ldb + (sch << 3);

    f32x4 acc[4][4];
    #pragma unroll
    for (int i = 0; i < 4; i++)
        #pragma unroll
        for (int j = 0; j < 4; j++) acc[i][j] = (f32x4){0.f, 0.f, 0.f, 0.f};

    const int nk = K >> 5;
    auto stage = [&](int ki, int buf) {
        const int ko = ki << 5;
        gl_lds16(Ag0 + ko, &As[buf][t << 3]);
        gl_lds16(Ag1 + ko, &As[buf][(t + 256) << 3]);
        gl_lds16(Bg0 + ko, &Bs[buf][t << 3]);
        gl_lds16(Bg1 + ko, &Bs[buf][(t + 256) << 3]);
    };
    stage(0, 0);
    if (nk > 1) { stage(1, 1); SYNC_VM(4); }
    else        { SYNC_VM(0); }

    int cur = 0;
    for (int ki = 0; ki < nk; ki++) {
        const bool st = (ki + 2 < nk);
        if (st) stage(ki + 2, cur == 0 ? 2 : cur - 1);
        short8 af[4], bf[4];
        #pragma unroll
        for (int i = 0; i < 4; i++) {
            const int r = wr + (i << 4) + fr;
            af[i] = *(const short8*)&As[cur][(r << 5) + ((fq ^ ((r >> 1) & 3)) << 3)];
        }
        #pragma unroll
        for (int j = 0; j < 4; j++) {
            const int c = wc + (j << 4) + fr;
            bf[j] = *(const short8*)&Bs[cur][(c << 5) + ((fq ^ ((c >> 1) & 3)) << 3)];
        }
        #pragma unroll
        for (int i = 0; i < 4; i++)
            #pragma unroll
            for (int j = 0; j < 4; j++)
                acc[i][j] = __builtin_amdgcn_mfma_f32_16x16x32_bf16(af[i], bf[j], acc[i][j], 0, 0, 0);
        if (ki + 1 < nk) {
            if (st) SYNC_VM(4);
            else    SYNC_VM(0);
        }
        cur = (cur == 2) ? 0 : cur + 1;
    }

    #pragma unroll
    for (int i = 0; i < 4; i++) {
        #pragma unroll
        for (int j = 0; j < 4; j++) {
            const int nl  = n0 + wc + (j << 4) + fr;
            const int mlb = m0 + wr + (i << 4) + (fq << 2);
            const float bsv = bias ? bias[nl] : 0.f;
            #pragma unroll
            for (int r = 0; r < 4; r++)
                Cf[(long)(mlb + r) * ldc + nl] = acc[i][j][r] + bsv;
        }
    }
}

// ---------------------------------------------------------------------------
// Fused attention v2 (KV-split-2, R12-proven): block per (q-tile 32, head,
// batch), 4 waves = {2 q-halves x 2 kv-halves}; flash combine via LDS.
// ---------------------------------------------------------------------------
__global__ __launch_bounds__(256) void attn_fused(
    const u16* __restrict__ qkb, const u16* __restrict__ kb_, int ldk,
    const u16* __restrict__ vt,
    const int* __restrict__ ids, u16* __restrict__ attc, int causal)
{
    __shared__ u16 Ks[2][4096];      // [kv-half][64 keys x 64 d]
    __shared__ u16 Vs[2][4096];      // [kv-half][64 d x 64 s]
    __shared__ short Ps[4][16][72];
    const int t = threadIdx.x, lane = t & 63, w = t >> 6;
    const int fr = lane & 15, fq = lane >> 4;
    const int qh = w & 1, kvh = w >> 1;
    const int q0 = blockIdx.x << 5, h = blockIdx.y, b = blockIdx.z;

    const u16* qp = qkb + (long)(b * 512 + q0 + (qh << 4) + fr) * 1024 + h * 64 + (fq << 3);
    short8 aq0 = *(const short8*)qp;
    short8 aq1 = *(const short8*)(qp + 32);

    const int sr = t >> 3, sc = (t & 7) ^ (sr & 7);
    const u16* kg0 = kb_ + (long)(b * 512 + sr) * ldk + h * 64 + (sc << 3);
    const u16* kg1 = kg0 + 32L * ldk;
    const u16* vg0 = vt + (long)b * S2W + (long)(h * 64 + sr) * 512 + (sc << 3);
    const u16* vg1 = vg0 + 32L * 512;

    unsigned pmask = 0;
    #pragma unroll
    for (int kt = 0; kt < 8; kt++)
        #pragma unroll
        for (int j = 0; j < 4; j++)
            if (ids[b * 512 + (kt << 6) + (j << 4) + fr] == PADID)
                pmask |= 1u << ((kt << 2) + j);

    const int nkt = causal ? (((q0 + 31) >> 6) + 1) : 8;
    const int nA = (nkt + 1) >> 1, nB = nkt - nA;
    const int myn = kvh ? nB : nA;

    float m[4], l[4]; f32x4 oc[4];
    #pragma unroll
    for (int r = 0; r < 4; r++) { m[r] = -INFINITY; l[r] = 0.f; oc[r] = (f32x4){0.f,0.f,0.f,0.f}; }

    for (int i = 0; i < nA; i++) {
        {
            const long soA = (long)(i << 6);
            gl_lds16(kg0 + soA * ldk, &Ks[0][t << 3]);
            gl_lds16(kg1 + soA * ldk, &Ks[0][(t + 256) << 3]);
            gl_lds16(vg0 + soA,       &Vs[0][t << 3]);
            gl_lds16(vg1 + soA,       &Vs[0][(t + 256) << 3]);
            if (i < nB) {
                const long soB = (long)((nA + i) << 6);
                gl_lds16(kg0 + soB * ldk, &Ks[1][t << 3]);
                gl_lds16(kg1 + soB * ldk, &Ks[1][(t + 256) << 3]);
                gl_lds16(vg0 + soB,       &Vs[1][t << 3]);
                gl_lds16(vg1 + soB,       &Vs[1][(t + 256) << 3]);
            }
        }
        __syncthreads();

        if (i < myn) {
            const int kt = (kvh ? nA : 0) + i;
            f32x4 sc4[4];
            #pragma unroll
            for (int j = 0; j < 4; j++) sc4[j] = (f32x4){0.f,0.f,0.f,0.f};
            #pragma unroll
            for (int j = 0; j < 4; j++) {
                const int rr = (j << 4) + fr;
                short8 bk0 = *(const short8*)&Ks[kvh][rr * 64 + ((fq ^ (rr & 7)) << 3)];
                short8 bk1 = *(const short8*)&Ks[kvh][rr * 64 + (((fq | 4) ^ (rr & 7)) << 3)];
                sc4[j] = __builtin_amdgcn_mfma_f32_16x16x32_bf16(aq0, bk0, sc4[j], 0, 0, 0);
                sc4[j] = __builtin_amdgcn_mfma_f32_16x16x32_bf16(aq1, bk1, sc4[j], 0, 0, 0);
            }
            const int s0 = kt << 6;
            #pragma unroll
            for (int r = 0; r < 4; r++) {
                const int qa = q0 + (qh << 4) + (fq << 2) + r;
                float mx = -INFINITY;
                #pragma unroll
                for (int j = 0; j < 4; j++) {
                    bool msk = ((pmask >> ((kt << 2) + j)) & 1) ||
                               (causal && (s0 + (j << 4) + fr) > qa);
                    float sv = msk ? -INFINITY : sc4[j][r] * 0.125f;
                    sc4[j][r] = sv;
                    mx = fmaxf(mx, sv);
                }
                mx = fmaxf(mx, __shfl_xor(mx, 1)); mx = fmaxf(mx, __shfl_xor(mx, 2));
                mx = fmaxf(mx, __shfl_xor(mx, 4)); mx = fmaxf(mx, __shfl_xor(mx, 8));
                float mnew  = fmaxf(m[r], mx);
                float scale = (mnew == -INFINITY) ? 1.f : __expf(m[r] - mnew);
                float ps = 0.f;
                #pragma unroll
                for (int j = 0; j < 4; j++) {
                    float p2 = (sc4[j][r] == -INFINITY) ? 0.f : __expf(sc4[j][r] - mnew);
                    sc4[j][r] = p2; ps += p2;
                }
                ps += __shfl_xor(ps, 1); ps += __shfl_xor(ps, 2);
                ps += __shfl_xor(ps, 4); ps += __shfl_xor(ps, 8);
                l[r] = l[r] * scale + ps;
                m[r] = mnew;
                #pragma unroll
                for (int j2 = 0; j2 < 4; j2++) oc[j2][r] *= scale;
            }
            #pragma unroll
            for (int r = 0; r < 4; r++)
                #pragma unroll
                for (int j = 0; j < 4; j++)
                    Ps[w][(fq << 2) + r][(j << 4) + fr] = (short)f2bf(sc4[j][r]);
            #pragma unroll
            for (int kc2 = 0; kc2 < 2; kc2++) {
                short8 pa = *(const short8*)&Ps[w][fr][(kc2 << 5) + (fq << 3)];
                #pragma unroll
                for (int j2 = 0; j2 < 4; j2++) {
                    const int rd = (j2 << 4) + fr;
                    const int cch = (((kc2 << 2) | fq) ^ (rd & 7));
                    short8 bv = *(const short8*)&Vs[kvh][rd * 64 + (cch << 3)];
                    oc[j2] = __builtin_amdgcn_mfma_f32_16x16x32_bf16(pa, bv, oc[j2], 0, 0, 0);
                }
            }
        }
        __syncthreads();
    }

    // ---- combine kv halves (reuse Ks/Vs LDS) ----
    float* Ob = (float*)&Ks[0][0];
    float* Ml = (float*)&Vs[0][0];
    if (kvh == 1) {
        #pragma unroll
        for (int r = 0; r < 4; r++) {
            const int row = (qh << 4) + (fq << 2) + r;
            Ml[(row << 1)]     = m[r];
            Ml[(row << 1) + 1] = l[r];
            #pragma unroll
            for (int j2 = 0; j2 < 4; j2++)
                Ob[(row << 6) + (j2 << 4) + fr] = oc[j2][r];
        }
    }
    __syncthreads();
    if (kvh == 0) {
        #pragma unroll
        for (int r = 0; r < 4; r++) {
            const int row = (qh << 4) + (fq << 2) + r;
            const float mB = Ml[(row << 1)], lB = Ml[(row << 1) + 1];
            const float mN = fmaxf(m[r], mB);
            float sA, sB;
            if (mN == -INFINITY) { sA = 0.f; sB = 0.f; }
            else {
                sA = (m[r] == -INFINITY) ? 0.f : __expf(m[r] - mN);
                sB = (mB   == -INFINITY) ? 0.f : __expf(mB   - mN);
            }
            const float L = l[r] * sA + lB * sB;
            const float inv = (L > 0.f) ? 1.f / L : 0.f;
            #pragma unroll
            for (int j2 = 0; j2 < 4; j2++) {
                float val = (oc[j2][r] * sA + Ob[(row << 6) + (j2 << 4) + fr] * sB) * inv;
                attc[(long)(b * 512 + q0 + (qh << 4) + (fq << 2) + r) * 512 +
                     h * 64 + (j2 << 4) + fr] = f2bf(val);
            }
        }
    }
}

// LayerNorm over D=512: 4 rows/block (wave per row). f32 in -> bf16 out.
__global__ __launch_bounds__(256) void ln_rows(
    const float* __restrict__ x, const float* __restrict__ g,
    const float* __restrict__ b, u16* __restrict__ out)
{
    int row  = blockIdx.x * 4 + (threadIdx.x >> 6);
    int lane = threadIdx.x & 63;
    const float* xr = x + (long)row * Dm;
    float v[8]; float s = 0.f;
    #pragma unroll
    for (int i = 0; i < 8; i++) { v[i] = xr[lane + (i << 6)]; s += v[i]; }
    #pragma unroll
    for (int o = 32; o > 0; o >>= 1) s += __shfl_xor(s, o);
    float mean = s * (1.f / 512.f);
    float q = 0.f;
    #pragma unroll
    for (int i = 0; i < 8; i++) { float d = v[i] - mean; q += d * d; }
    #pragma unroll
    for (int o = 32; o > 0; o >>= 1) q += __shfl_xor(q, o);
    float rinv = rsqrtf(q * (1.f / 512.f) + LNEPS);
    u16* orow = out + (long)row * Dm;
    #pragma unroll
    for (int i = 0; i < 8; i++) {
        int c = lane + (i << 6);
        orow[c] = f2bf((v[i] - mean) * rinv * g[c] + b[c]);
    }
}

// Both embeddings in one launch: z=0 -> src->x, z=1 -> tgt->y. f32 out.
__global__ __launch_bounds__(256) void embed_pe2(
    const int* __restrict__ src, const int* __restrict__ tgt,
    const float* __restrict__ semb, const float* __restrict__ temb,
    float* __restrict__ xo, float* __restrict__ yo)
{
    const int zz = blockIdx.y;
    const int* ids = zz ? tgt : src;
    const float* emb = zz ? temb : semb;
    float* out = zz ? yo : xo;
    int idx = blockIdx.x * 256 + threadIdx.x;   // NTOK*512 = 2^20
    int d   = idx & 511;
    int tok = idx >> 9;
    int s   = tok & 511;
    int id  = ids[tok];
    float val = emb[(long)id * Dm + d] * 22.62741699796952f;     // sqrt(512)
    int i2 = d >> 1;
    float dv  = expf((float)(i2 << 1) * (-9.210340371976184f / 512.f));
    float ang = (float)s * dv;
    val += (d & 1) ? cosf(ang) : sinf(ang);
    out[idx] = val;
}

// ---------------------------------------------------------------------------
extern "C" void kernel_launch(void* const* d_in, const int* in_sizes, int n_in,
                              void* d_out, int out_size, void* d_ws, size_t ws_size,
                              hipStream_t stream)
{
    (void)in_sizes; (void)n_in; (void)out_size; (void)ws_size;
    const int*   src       = (const int*)d_in[0];
    const int*   tgt       = (const int*)d_in[1];
    const float* src_embed = (const float*)d_in[2];
    const float* tgt_embed = (const float*)d_in[3];
    const float* enc_b1  = (const float*)d_in[9];
    const float* enc_b2  = (const float*)d_in[11];
    const float* enc_ln1g = (const float*)d_in[12];
    const float* enc_ln1b = (const float*)d_in[13];
    const float* enc_ln2g = (const float*)d_in[14];
    const float* enc_ln2b = (const float*)d_in[15];
    const float* enc_lnfg = (const float*)d_in[16];
    const float* enc_lnfb = (const float*)d_in[17];
    const float* dec_b1  = (const float*)d_in[27];
    const float* dec_b2  = (const float*)d_in[29];
    const float* dec_ln1g = (const float*)d_in[30];
    const float* dec_ln1b = (const float*)d_in[31];
    const float* dec_ln2g = (const float*)d_in[32];
    const float* dec_ln2b = (const float*)d_in[33];
    const float* dec_ln3g = (const float*)d_in[34];
    const float* dec_ln3b = (const float*)d_in[35];
    const float* dec_lnfg = (const float*)d_in[36];
    const float* dec_lnfb = (const float*)d_in[37];
    const float* out_b  = (const float*)d_in[39];

    char* wp = (char*)d_ws;
    auto carve = [&](size_t nbytes) {
        void* p = (void*)wp; wp += (nbytes + 255) & ~(size_t)255; return p;
    };

    const long nW = (long)NLay * S2W;
    const long nF = (long)NLay * DFFm * Dm;
    const long nO = 32000L * Dm;

    u16* Wb[12];
    for (int i = 0; i < 12; i++) Wb[i] = (u16*)carve((size_t)nW * 2);
    u16* w1E  = (u16*)carve((size_t)nF * 2);
    u16* w2E  = (u16*)carve((size_t)nF * 2);
    u16* w1D  = (u16*)carve((size_t)nF * 2);
    u16* w2D  = (u16*)carve((size_t)nF * 2);
    u16* outW = (u16*)carve((size_t)nO * 2);

    float* x  = (float*)carve((size_t)NTOK * Dm * 4);
    float* y  = (float*)carve((size_t)NTOK * Dm * 4);
    u16* nrm  = (u16*)carve((size_t)NTOK * Dm * 2);
    u16* qkb  = (u16*)carve((size_t)NTOK * 1024 * 2);
    u16* vt   = (u16*)carve((size_t)Bb * Dm * 512 * 2);
    u16* attc = (u16*)carve((size_t)NTOK * Dm * 2);
    u16* h1   = (u16*)carve((size_t)NTOK * DFFm * 2);
    u16* memn = (u16*)carve((size_t)NTOK * Dm * 2);
    u16* kc6  = (u16*)carve((size_t)NLay * NTOK * 512 * 2);   // cross K, per layer
    u16* vt6  = (u16*)carve((size_t)NLay * Bb * S2W * 2);     // cross V^T, per layer

    const int wi[12] = {4, 5, 6, 7, 18, 19, 20, 21, 22, 23, 24, 25};
    CvtJobs jobs;
    for (int i = 0; i < 12; i++) {
        jobs.s[i] = (const float*)d_in[wi[i]]; jobs.d[i] = Wb[i]; jobs.n4[i] = nW >> 2;
    }
    jobs.s[12] = (const float*)d_in[8];  jobs.d[12] = w1E;  jobs.n4[12] = nF >> 2;
    jobs.s[13] = (const float*)d_in[10]; jobs.d[13] = w2E;  jobs.n4[13] = nF >> 2;
    jobs.s[14] = (const float*)d_in[26]; jobs.d[14] = w1D;  jobs.n4[14] = nF >> 2;
    jobs.s[15] = (const float*)d_in[28]; jobs.d[15] = w2D;  jobs.n4[15] = nF >> 2;
    jobs.s[16] = (const float*)d_in[38]; jobs.d[16] = outW; jobs.n4[16] = nO >> 2;
    cvt_many<<<dim3(512, 17), 256, 0, stream>>>(jobs);

    const int BIG = 1 << 28;
    u16 *eWq = Wb[0], *eWk = Wb[1], *eWv = Wb[2], *eWo = Wb[3];
    u16 *sWq = Wb[4], *sWk = Wb[5], *sWv = Wb[6], *sWo = Wb[7];
    u16 *cWq = Wb[8], *cWk = Wb[9], *cWv = Wb[10], *cWo = Wb[11];

    // both embeddings up front (decoder stream doesn't depend on encoder here)
    embed_pe2<<<dim3(4096, 2), 256, 0, stream>>>(src, tgt, src_embed, tgt_embed, x, y);

    // ---------------- Encoder ----------------
    for (int l = 0; l < NLay; l++) {
        const size_t wo = (size_t)l * S2W;
        ln_rows<<<512, 256, 0, stream>>>(x, enc_ln1g + l * Dm, enc_ln1b + l * Dm, nrm);
        gemm_bt<<<dim3(24, 32, 1), 256, 0, stream>>>(nrm, nrm, nrm, 512,
            eWq + wo, eWk + wo, eWv + wo, 512,
            nullptr, qkb, 1024, nullptr, 0, 512, 1, 1024, 0, vt);
        attn_fused<<<dim3(16, Hh, Bb), 256, 0, stream>>>(qkb, qkb + 512, 1024, vt, src, attc, 0);
        gemm_bt<<<dim3(8, 32, 2), 256, 0, stream>>>(attc, attc, attc, 512,
            eWo + wo, nullptr, nullptr, 512,
            x, nullptr, 512, nullptr, 0, 256, 2, BIG, 0, nullptr);
        ln_rows<<<512, 256, 0, stream>>>(x, enc_ln2g + l * Dm, enc_ln2b + l * Dm, nrm);
        gemm_bt<<<dim3(32, 32, 1), 256, 0, stream>>>(nrm, nrm, nrm, 512,
            w1E + (size_t)l * DFFm * Dm, nullptr, nullptr, 512,
            nullptr, h1, DFFm, enc_b1 + l * DFFm, 1, 512, 1, BIG, 0, nullptr);
        gemm_bt<<<dim3(8, 32, 4), 256, 0, stream>>>(h1, h1, h1, DFFm,
            w2E + (size_t)l * Dm * DFFm, nullptr, nullptr, DFFm,
            x, nullptr, 512, enc_b2 + l * Dm, 0, 512, 4, BIG, 0, nullptr);
    }
    ln_rows<<<512, 256, 0, stream>>>(x, enc_lnfg, enc_lnfb, memn);
    gemm_kv6<<<dim3(16, 32, NLay), 256, 0, stream>>>(memn, cWk, cWv, kc6, vt6);

    // ---------------- Decoder ----------------
    for (int l = 0; l < NLay; l++) {
        const size_t wo = (size_t)l * S2W;
        // self-attention (causal + tgt pad)
        ln_rows<<<512, 256, 0, stream>>>(y, dec_ln1g + l * Dm, dec_ln1b + l * Dm, nrm);
        gemm_bt<<<dim3(24, 32, 1), 256, 0, stream>>>(nrm, nrm, nrm, 512,
            sWq + wo, sWk + wo, sWv + wo, 512,
            nullptr, qkb, 1024, nullptr, 0, 512, 1, 1024, 0, vt);
        attn_fused<<<dim3(16, Hh, Bb), 256, 0, stream>>>(qkb, qkb + 512, 1024, vt, tgt, attc, 1);
        gemm_bt<<<dim3(8, 32, 2), 256, 0, stream>>>(attc, attc, attc, 512,
            sWo + wo, nullptr, nullptr, 512,
            y, nullptr, 512, nullptr, 0, 256, 2, BIG, 0, nullptr);
        // cross-attention: Q only (K/V precomputed by gemm_kv6)
        ln_rows<<<512, 256, 0, stream>>>(y, dec_ln2g + l * Dm, dec_ln2b + l * Dm, nrm);
        gemm_bt<<<dim3(8, 32, 1), 256, 0, stream>>>(nrm, nrm, nrm, 512,
            cWq + wo, nullptr, nullptr, 512,
            nullptr, qkb, 1024, nullptr, 0, 512, 1, BIG, 0, nullptr);
        attn_fused<<<dim3(16, Hh, Bb), 256, 0, stream>>>(qkb,
            kc6 + (size_t)l * NTOK * 512, 512, vt6 + (size_t)l * Bb * S2W, src, attc, 0);
        gemm_bt<<<dim3(8, 32, 2), 256, 0, stream>>>(attc, attc, attc, 512,
            cWo + wo, nullptr, nullptr, 512,
            y, nullptr, 512, nullptr, 0, 256, 2, BIG, 0, nullptr);
        // FFN
        ln_rows<<<512, 256, 0, stream>>>(y, dec_ln3g + l * Dm, dec_ln3b + l * Dm, nrm);
        gemm_bt<<<dim3(32, 32, 1), 256, 0, stream>>>(nrm, nrm, nrm, 512,
            w1D + (size_t)l * DFFm * Dm, nullptr, nullptr, 512,
            nullptr, h1, DFFm, dec_b1 + l * DFFm, 1, 512, 1, BIG, 0, nullptr);
        gemm_bt<<<dim3(8, 32, 4), 256, 0, stream>>>(h1, h1, h1, DFFm,
            w2D + (size_t)l * Dm * DFFm, nullptr, nullptr, DFFm,
            y, nullptr, 512, dec_b2 + l * Dm, 0, 512, 4, BIG, 0, nullptr);
    }
    ln_rows<<<512, 256, 0, stream>>>(y, dec_lnfg, dec_lnfb, nrm);

    // final projection to vocab: [2048][32000] f32 out
    gemm_big<<<dim3(250, 16), 256, 0, stream>>>(nrm, 512, outW, 512,
        (float*)d_out, 32000, out_b, 512);
}